// Round 14
// baseline (124.491 us; speedup 1.0000x reference)
//
#include <hip/hip_runtime.h>
#include <math.h>

// Problem constants
#define BB 16
#define LQ 576
#define LT 512
#define DD 768
#define HH 12
#define DH 64
#define TOPK 64

typedef __attribute__((ext_vector_type(8))) short bf16x8;
typedef __attribute__((ext_vector_type(4))) float f32x4;
typedef __attribute__((ext_vector_type(4))) unsigned short u16x4;

// Workspace layout (float offsets)
static constexpr size_t XQBF  = 0;          // 9216*768 bf16 (xq_n; reused as attn-out ABF)
static constexpr size_t XKVBF = 3538944;    // 8192*768 bf16
static constexpr size_t WQB   = 6684672;    // 768*768 bf16
static constexpr size_t WKB   = 6979584;    // wk bf16
static constexpr size_t WVB   = 7274496;    // wv bf16
static constexpr size_t WOB   = 7569408;    // wo bf16
static constexpr size_t QBFo  = 7864320;    // 9216*768 bf16 (pre-scaled by 0.125)
static constexpr size_t GSo   = 11409408;   // 8192*16 f32 gate scores
static constexpr size_t UFo   = 11540480;   // 768*16 f32 (u transposed [c][h]; h>=12 zero)
static constexpr size_t IDXo  = 17694720;   // 192*64 int
static constexpr size_t VBIA  = 17707008;   // 192*64 f32 (0 or -inf)
static constexpr size_t NDVo  = 17719296;   // 192 f32
static constexpr size_t GHo   = 17719488;   // 192 f32
static constexpr size_t KCo   = 17719680;   // 192*64*64 bf16 (kept K, rank order)
static constexpr size_t VCTo  = 18112896;   // 192*64*64 bf16 (V^T compact [d][j])

__device__ inline unsigned short f2bf(float f) {
  union { float f; unsigned u; } v; v.f = f;
  unsigned r = v.u + 0x7FFFu + ((v.u >> 16) & 1u);
  return (unsigned short)(r >> 16);
}
__device__ inline float bf2f(unsigned short u) {
  union { unsigned u; float f; } v; v.u = ((unsigned)u) << 16;
  return v.f;
}
__device__ inline void gload_lds16(const void* src, void* dst) {
  __builtin_amdgcn_global_load_lds((const __attribute__((address_space(1))) void*)src,
                                   (__attribute__((address_space(3))) void*)dst, 16, 0, 0);
}
// compiler-invisible LDS read (no alias edge to outstanding global_load_lds)
__device__ inline bf16x8 lds_read16(const unsigned short* p) {
  bf16x8 r;
  asm volatile("ds_read_b128 %0, %1"
               : "=v"(r)
               : "v"((const __attribute__((address_space(3))) unsigned short*)p));
  return r;
}

// ---------------- LayerNorm -> bf16 (+ fused gate scores on the kv half) ----------------
__global__ __launch_bounds__(256) void ln_all(const float* __restrict__ xq,
                                              const float* __restrict__ xkv,
                                              const float* __restrict__ gq,
                                              const float* __restrict__ bq,
                                              const float* __restrict__ gkv,
                                              const float* __restrict__ bkv,
                                              unsigned short* __restrict__ yq,
                                              unsigned short* __restrict__ ykv,
                                              const float* __restrict__ UF,
                                              float* __restrict__ GS) {
  int row = blockIdx.x;
  const float *xr, *gg, *bb;
  unsigned short* yr;
  bool kvhalf = (row >= BB * LQ);
  if (!kvhalf) {
    xr = xq + (size_t)row * DD; gg = gq; bb = bq; yr = yq + (size_t)row * DD;
  } else {
    int r = row - BB * LQ;
    xr = xkv + (size_t)r * DD; gg = gkv; bb = bkv; yr = ykv + (size_t)r * DD;
  }
  int t = threadIdx.x;
  float v0 = xr[t], v1 = xr[t + 256], v2 = xr[t + 512];
  __shared__ float red[4];
  __shared__ float wg[4][12];
  float s = v0 + v1 + v2;
  #pragma unroll
  for (int o = 32; o > 0; o >>= 1) s += __shfl_xor(s, o);
  if ((t & 63) == 0) red[t >> 6] = s;
  __syncthreads();
  float m = (red[0] + red[1] + red[2] + red[3]) * (1.0f / 768.0f);
  float d0 = v0 - m, d1 = v1 - m, d2 = v2 - m;
  float s2 = d0 * d0 + d1 * d1 + d2 * d2;
  #pragma unroll
  for (int o = 32; o > 0; o >>= 1) s2 += __shfl_xor(s2, o);
  __syncthreads();
  if ((t & 63) == 0) red[t >> 6] = s2;
  __syncthreads();
  float var = (red[0] + red[1] + red[2] + red[3]) * (1.0f / 768.0f);
  float rs = rsqrtf(var + 1e-5f);
  float y0 = d0 * rs * gg[t]       + bb[t];
  float y1 = d1 * rs * gg[t + 256] + bb[t + 256];
  float y2 = d2 * rs * gg[t + 512] + bb[t + 512];
  yr[t]       = f2bf(y0);
  yr[t + 256] = f2bf(y1);
  yr[t + 512] = f2bf(y2);
  if (kvhalf) {
    // gs[r,h] = sum_c y[c] * UF[c][h]  (12 heads)
    int r = row - BB * LQ;
    float p[12];
    #pragma unroll
    for (int h = 0; h < 12; ++h) p[h] = 0.0f;
    #pragma unroll
    for (int j = 0; j < 3; ++j) {
      float yv = (j == 0) ? y0 : (j == 1 ? y1 : y2);
      const float4* ur = reinterpret_cast<const float4*>(&UF[(size_t)(t + j * 256) * 16]);
      #pragma unroll
      for (int q4 = 0; q4 < 3; ++q4) {
        float4 u4 = ur[q4];
        p[q4 * 4 + 0] += yv * u4.x;
        p[q4 * 4 + 1] += yv * u4.y;
        p[q4 * 4 + 2] += yv * u4.z;
        p[q4 * 4 + 3] += yv * u4.w;
      }
    }
    #pragma unroll
    for (int h = 0; h < 12; ++h) {
      float v = p[h];
      #pragma unroll
      for (int o = 32; o > 0; o >>= 1) v += __shfl_xor(v, o);
      if ((t & 63) == 0) wg[t >> 6][h] = v;
    }
    __syncthreads();
    if (t < 12)
      GS[(size_t)r * 16 + t] = wg[0][t] + wg[1][t] + wg[2][t] + wg[3][t];
  }
}

// ---------------- weight converts + u precompute (one launch, 5 y-slices) ----------------
__global__ __launch_bounds__(256) void conv4u(const float* __restrict__ s0, const float* __restrict__ s1,
                                              const float* __restrict__ s2, const float* __restrict__ s3,
                                              unsigned short* d0, unsigned short* d1,
                                              unsigned short* d2, unsigned short* d3,
                                              const float* __restrict__ hq,
                                              float* __restrict__ UF) {
  int t = threadIdx.x;
  if (blockIdx.y == 4) {
    int h = blockIdx.x;
    if (h >= 16) return;
    if (h < HH) {
      float a0 = 0.0f, a1 = 0.0f, a2 = 0.0f;
      for (int d = 0; d < DH; ++d) {
        float sc = hq[h * DH + d];
        const float* wr = s1 + (size_t)(h * DH + d) * DD;
        a0 += sc * wr[t]; a1 += sc * wr[t + 256]; a2 += sc * wr[t + 512];
      }
      UF[(size_t)t * 16 + h]         = a0 * 0.125f;
      UF[(size_t)(t + 256) * 16 + h] = a1 * 0.125f;
      UF[(size_t)(t + 512) * 16 + h] = a2 * 0.125f;
    } else {
      UF[(size_t)t * 16 + h]         = 0.0f;
      UF[(size_t)(t + 256) * 16 + h] = 0.0f;
      UF[(size_t)(t + 512) * 16 + h] = 0.0f;
    }
    return;
  }
  const float* s; unsigned short* d;
  switch (blockIdx.y) {
    case 0: s = s0; d = d0; break;
    case 1: s = s1; d = d1; break;
    case 2: s = s2; d = d2; break;
    default: s = s3; d = d3; break;
  }
  int i = (blockIdx.x * 256 + t) * 4;
  float4 v = *reinterpret_cast<const float4*>(&s[i]);
  u16x4 o = { f2bf(v.x), f2bf(v.y), f2bf(v.z), f2bf(v.w) };
  *reinterpret_cast<u16x4*>(&d[i]) = o;
}

// ===== common GEMM machinery (counted-vmcnt 2-phase, T4; asm ds_read) =====

#define COMMON_PREAMBLE()                                                      \
  const int tid = threadIdx.x;                                                 \
  const int w = tid >> 6, l = tid & 63;                                        \
  const int lq = l & 15, g = l >> 4;                                           \
  const int srow = l >> 3;                                                     \
  const int scol = ((l & 7) * 16) ^ ((srow & 7) << 4);

// 8 VMEM per wave per stage (4 A + 4 B); 128x128 tile, BK=64
#define STAGE2(BUFI, T)                                                        \
  {                                                                            \
    int k0s = (T) * 64;                                                        \
    _Pragma("unroll")                                                          \
    for (int it = 0; it < 4; ++it) {                                           \
      int rbase = it * 32 + w * 8;                                             \
      gload_lds16(Asrc + (size_t)rbase * DD + k0s, &As[BUFI][rbase * 64]);     \
      gload_lds16(Bsrc + (size_t)rbase * DD + k0s, &Bs[BUFI][rbase * 64]);     \
    }                                                                          \
  }

#define COMPUTE2(BUFI)                                                         \
  {                                                                            \
    bf16x8 a[4][2], b[4][2];                                                   \
    _Pragma("unroll")                                                          \
    for (int mi = 0; mi < 4; ++mi)                                             \
      _Pragma("unroll")                                                        \
      for (int ks = 0; ks < 2; ++ks) {                                         \
        a[mi][ks] = lds_read16(&As[BUFI][aoff[mi][ks]]);                       \
        b[mi][ks] = lds_read16(&Bs[BUFI][boff[mi][ks]]);                       \
      }                                                                        \
    asm volatile("s_waitcnt lgkmcnt(0)" ::: "memory");                         \
    __builtin_amdgcn_sched_barrier(0);                                         \
    _Pragma("unroll")                                                          \
    for (int ks = 0; ks < 2; ++ks)                                             \
      _Pragma("unroll")                                                        \
      for (int mi = 0; mi < 4; ++mi)                                           \
        _Pragma("unroll")                                                      \
        for (int ni = 0; ni < 4; ++ni)                                         \
          acc[mi][ni] = __builtin_amdgcn_mfma_f32_16x16x32_bf16(               \
              a[mi][ks], b[ni][ks], acc[mi][ni], 0, 0, 0);                     \
  }

#define GEMM_MAIN()                                                            \
  int aoff[4][2], boff[4][2];                                                  \
  _Pragma("unroll")                                                            \
  for (int mi = 0; mi < 4; ++mi) {                                             \
    int rowa = wr * 64 + mi * 16 + lq;                                         \
    int rowb = wc * 64 + mi * 16 + lq;                                         \
    _Pragma("unroll")                                                          \
    for (int ks = 0; ks < 2; ++ks) {                                           \
      aoff[mi][ks] = rowa * 64 + (((ks * 64 + g * 16) ^ ((rowa & 7) << 4)) >> 1); \
      boff[mi][ks] = rowb * 64 + (((ks * 64 + g * 16) ^ ((rowb & 7) << 4)) >> 1); \
    }                                                                          \
  }                                                                            \
  STAGE2(0, 0);                                                                \
  STAGE2(1, 1);                                                                \
  _Pragma("unroll")                                                            \
  for (int t = 0; t < 12; ++t) {                                               \
    if (t < 11) asm volatile("s_waitcnt vmcnt(8)" ::: "memory");               \
    else        asm volatile("s_waitcnt vmcnt(0)" ::: "memory");               \
    __builtin_amdgcn_sched_barrier(0);                                         \
    __builtin_amdgcn_s_barrier();                                              \
    if ((t & 1) == 0) { COMPUTE2(0); } else { COMPUTE2(1); }                   \
    __builtin_amdgcn_s_barrier();                                              \
    __builtin_amdgcn_sched_barrier(0);                                         \
    if (t + 2 < 12) {                                                          \
      if ((t & 1) == 0) { STAGE2(0, t + 2); } else { STAGE2(1, t + 2); }       \
    }                                                                          \
  }

// ---------------- Gate + top-k (scores precomputed; g = sum p*s) ----------------
__global__ __launch_bounds__(512) void gate_topk(const float* __restrict__ GS,
                                                 const int* __restrict__ mask,
                                                 int* __restrict__ idxo,
                                                 float* __restrict__ vbias,
                                                 float* __restrict__ ndv,
                                                 float* __restrict__ g_h) {
  int bh = blockIdx.x, b = bh / HH, h = bh % HH;
  int l = threadIdx.x;
  __shared__ float s_sc[512];
  __shared__ float red[8];
  __shared__ int wred[8];
  float sc = GS[(size_t)(b * LT + l) * 16 + h];
  bool maskv = (mask[b * LT + l] != 0);
  if (!maskv) sc = -INFINITY;
  s_sc[l] = sc;
  float m0 = sc;
  #pragma unroll
  for (int o = 32; o > 0; o >>= 1) m0 = fmaxf(m0, __shfl_xor(m0, o));
  if ((l & 63) == 0) red[l >> 6] = m0;
  __syncthreads();
  float m = red[0];
  #pragma unroll
  for (int w = 1; w < 8; w++) m = fmaxf(m, red[w]);
  float p = __expf(sc - m);
  float s1 = p;
  #pragma unroll
  for (int o = 32; o > 0; o >>= 1) s1 += __shfl_xor(s1, o);
  __syncthreads();
  if ((l & 63) == 0) red[l >> 6] = s1;
  __syncthreads();
  float Z = 0.0f;
  #pragma unroll
  for (int w = 0; w < 8; w++) Z += red[w];
  p /= Z;
  float gc = maskv ? p * sc : 0.0f;
  #pragma unroll
  for (int o = 32; o > 0; o >>= 1) gc += __shfl_xor(gc, o);
  __syncthreads();
  if ((l & 63) == 0) red[l >> 6] = gc;
  __syncthreads();
  if (l == 0) {
    float G = 0.0f;
    #pragma unroll
    for (int w = 0; w < 8; w++) G += red[w];
    g_h[bh] = 1.0f / (1.0f + __expf(-G));
  }
  float my = s_sc[l];
  int cnt = 0;
  for (int j = 0; j < LT; j++) {
    float sj = s_sc[j];
    cnt += (sj > my || (sj == my && j < l)) ? 1 : 0;
  }
  if (cnt < TOPK) {
    idxo[bh * TOPK + cnt] = l;
    vbias[bh * TOPK + cnt] = maskv ? 0.0f : -INFINITY;
  }
  int dv = (maskv && cnt >= TOPK) ? 1 : 0;
  unsigned long long bal = __ballot(dv);
  if ((l & 63) == 0) wred[l >> 6] = __popcll(bal);
  __syncthreads();
  if (l == 0) {
    int nd = 0;
    #pragma unroll
    for (int w = 0; w < 8; w++) nd += wred[w];
    ndv[bh] = (float)nd;
  }
}

// ---------------- fused: Q projection (432 blocks) + compact K&V gather-GEMM (192 blocks) ----------------
__global__ __launch_bounds__(256, 2) void proj2(const unsigned short* __restrict__ xqb,
                                                const unsigned short* __restrict__ wqb,
                                                const unsigned short* __restrict__ xkvb,
                                                const unsigned short* __restrict__ wkb,
                                                const unsigned short* __restrict__ wvb,
                                                const int* __restrict__ idxo,
                                                unsigned short* __restrict__ QBF,
                                                unsigned short* __restrict__ KC,
                                                unsigned short* __restrict__ VCT) {
  __shared__ __align__(16) unsigned short As[2][128 * 64];
  __shared__ __align__(16) unsigned short Bs[2][128 * 64];
  __shared__ int sidx[64];
  COMMON_PREAMBLE();
  int p = blockIdx.x;                       // 624 = 8 * 78
  int bid = (p & 7) * 78 + (p >> 3);

  if (bid < 432) {
    // ---- Q projection, 128x128 tile ----
    const int wr = w >> 1, wc = w & 1;
    const int mtile = bid / 6, nt = bid % 6;
    const int bm = mtile * 128, bn = nt * 128;
    const unsigned short* Asrc = xqb + (size_t)(bm + srow) * DD + (scol >> 1);
    const unsigned short* Bsrc = wqb + (size_t)(bn + srow) * DD + (scol >> 1);
    f32x4 acc[4][4] = {};
    GEMM_MAIN();
    const int m_base = bm + wr * 64, n_base = bn + wc * 64;
    #pragma unroll
    for (int mi = 0; mi < 4; ++mi)
      #pragma unroll
      for (int r = 0; r < 4; ++r) {
        int m = m_base + mi * 16 + g * 4 + r;
        #pragma unroll
        for (int ni = 0; ni < 4; ++ni) {
          int n = n_base + ni * 16 + lq;
          QBF[(size_t)m * DD + n] = f2bf(acc[mi][ni][r] * 0.125f);
        }
      }
  } else {
    // ---- compact K & V: per (b,h), Kc[j,d] / Vct[d,j], 64x64x768 gather-GEMM ----
    const int bh = bid - 432, b = bh / HH, h = bh % HH;
    if (tid < 64) sidx[tid] = idxo[bh * TOPK + tid];
    __syncthreads();
    unsigned short* Xs0 = &As[0][0]; unsigned short* Xs1 = &As[0][4096];
    unsigned short* Kp0 = &As[1][0]; unsigned short* Kp1 = &As[1][4096];
    unsigned short* Vp0 = &Bs[0][0]; unsigned short* Vp1 = &Bs[0][4096];
    const int j0 = w * 16 + srow, j1 = w * 16 + 8 + srow;
    const unsigned short* xs0 = xkvb + (size_t)(b * LT + sidx[j0]) * DD + (scol >> 1);
    const unsigned short* xs1 = xkvb + (size_t)(b * LT + sidx[j1]) * DD + (scol >> 1);
    const unsigned short* wk0 = wkb + (size_t)(h * DH + j0) * DD + (scol >> 1);
    const unsigned short* wk1 = wkb + (size_t)(h * DH + j1) * DD + (scol >> 1);
    const unsigned short* wv0 = wvb + (size_t)(h * DH + j0) * DD + (scol >> 1);
    const unsigned short* wv1 = wvb + (size_t)(h * DH + j1) * DD + (scol >> 1);

#define KV_STAGE(Xd, Kd, Vd, T)                                                \
    {                                                                          \
      int k0s = (T) * 64;                                                      \
      gload_lds16(xs0 + k0s, Xd + (w * 16) * 64);                              \
      gload_lds16(xs1 + k0s, Xd + (w * 16 + 8) * 64);                          \
      gload_lds16(wk0 + k0s, Kd + (w * 16) * 64);                              \
      gload_lds16(wk1 + k0s, Kd + (w * 16 + 8) * 64);                          \
      gload_lds16(wv0 + k0s, Vd + (w * 16) * 64);                              \
      gload_lds16(wv1 + k0s, Vd + (w * 16 + 8) * 64);                          \
    }

    f32x4 accK[4] = {}, accV[4] = {};

#define KV_COMPUTE(Xd, Kd, Vd)                                                 \
    {                                                                          \
      bf16x8 ax[2], av[2], bk[4][2], bx[4][2];                                 \
      _Pragma("unroll")                                                        \
      for (int ks = 0; ks < 2; ++ks) {                                         \
        int arow = w * 16 + lq;                                                \
        int acb = (ks * 64 + g * 16) ^ ((arow & 7) << 4);                      \
        ax[ks] = lds_read16(Xd + arow * 64 + (acb >> 1));                      \
        av[ks] = lds_read16(Vd + arow * 64 + (acb >> 1));                      \
        _Pragma("unroll")                                                      \
        for (int ni = 0; ni < 4; ++ni) {                                       \
          int brow = ni * 16 + lq;                                             \
          int bcb = (ks * 64 + g * 16) ^ ((brow & 7) << 4);                    \
          bk[ni][ks] = lds_read16(Kd + brow * 64 + (bcb >> 1));                \
          bx[ni][ks] = lds_read16(Xd + brow * 64 + (bcb >> 1));                \
        }                                                                      \
      }                                                                        \
      asm volatile("s_waitcnt lgkmcnt(0)" ::: "memory");                       \
      __builtin_amdgcn_sched_barrier(0);                                       \
      _Pragma("unroll")                                                        \
      for (int ks = 0; ks < 2; ++ks)                                           \
        _Pragma("unroll")                                                      \
        for (int ni = 0; ni < 4; ++ni) {                                       \
          accK[ni] = __builtin_amdgcn_mfma_f32_16x16x32_bf16(ax[ks], bk[ni][ks], accK[ni], 0, 0, 0); \
          accV[ni] = __builtin_amdgcn_mfma_f32_16x16x32_bf16(av[ks], bx[ni][ks], accV[ni], 0, 0, 0); \
        }                                                                      \
    }

    KV_STAGE(Xs0, Kp0, Vp0, 0);
    KV_STAGE(Xs1, Kp1, Vp1, 1);
    #pragma unroll
    for (int t = 0; t < 12; ++t) {
      if (t < 11) asm volatile("s_waitcnt vmcnt(6)" ::: "memory");
      else        asm volatile("s_waitcnt vmcnt(0)" ::: "memory");
      __builtin_amdgcn_sched_barrier(0);
      __builtin_amdgcn_s_barrier();
      if ((t & 1) == 0) { KV_COMPUTE(Xs0, Kp0, Vp0); } else { KV_COMPUTE(Xs1, Kp1, Vp1); }
      __builtin_amdgcn_s_barrier();
      __builtin_amdgcn_sched_barrier(0);
      if (t + 2 < 12) {
        if ((t & 1) == 0) { KV_STAGE(Xs0, Kp0, Vp0, t + 2); } else { KV_STAGE(Xs1, Kp1, Vp1, t + 2); }
      }
    }
    #pragma unroll
    for (int ni = 0; ni < 4; ++ni)
      #pragma unroll
      for (int r = 0; r < 4; ++r) {
        int mrow = w * 16 + g * 4 + r;
        KC [(size_t)bh * 4096 + mrow * 64 + ni * 16 + lq] = f2bf(accK[ni][r]);
        VCT[(size_t)bh * 4096 + mrow * 64 + ni * 16 + lq] = f2bf(accV[ni][r]);
      }
  }
}

// ---------------- output projection GEMM + residual epilogue ----------------
__global__ __launch_bounds__(256, 2) void o_gemm(const unsigned short* __restrict__ ABF,
                                                 const unsigned short* __restrict__ wob,
                                                 float* __restrict__ out,
                                                 const float* __restrict__ resid,
                                                 const float* __restrict__ gl) {
  __shared__ __align__(16) unsigned short As[2][128 * 64];
  __shared__ __align__(16) unsigned short Bs[2][128 * 64];
  COMMON_PREAMBLE();
  const int wr = w >> 1, wc = w & 1;
  int p = blockIdx.x;                     // 432 = 8 * 54
  int bid = (p & 7) * 54 + (p >> 3);
  const int mtile = bid / 6, nt = bid % 6;
  const int bm = mtile * 128, bn = nt * 128;
  const unsigned short* Asrc = ABF + (size_t)(bm + srow) * DD + (scol >> 1);
  const unsigned short* Bsrc = wob + (size_t)(bn + srow) * DD + (scol >> 1);

  f32x4 acc[4][4] = {};
  GEMM_MAIN();

  float alpha = 1.0f / (1.0f + __expf(-gl[0]));
  const int m_base = bm + wr * 64, n_base = bn + wc * 64;
  #pragma unroll
  for (int mi = 0; mi < 4; ++mi)
    #pragma unroll
    for (int r = 0; r < 4; ++r) {
      int m = m_base + mi * 16 + g * 4 + r;
      #pragma unroll
      for (int ni = 0; ni < 4; ++ni) {
        int n = n_base + ni * 16 + lq;
        out[(size_t)m * DD + n] = resid[(size_t)m * DD + n] + alpha * acc[mi][ni][r];
      }
    }
}

// ---------------- Top-k attention: single 64-key tile, closed-form dropped-mass correction ----------------
__global__ __launch_bounds__(256) void attn_topk(const unsigned short* __restrict__ Qb,
                                                 const unsigned short* __restrict__ KC,
                                                 const unsigned short* __restrict__ VCT,
                                                 const float* __restrict__ vbias,
                                                 const float* __restrict__ ndv,
                                                 const float* __restrict__ g_h,
                                                 unsigned short* __restrict__ att) {
  const int bh = blockIdx.y, b = bh / HH, h = bh % HH;
  const int q0 = blockIdx.x * 64;
  const int tid = threadIdx.x;
  const int w = tid >> 6, l = tid & 63;
  const int lq = l & 15, g = l >> 4;

  __shared__ __align__(16) unsigned short Klds[64 * 64];
  __shared__ __align__(16) unsigned short Vlds[64 * 64];
  __shared__ float svb[64];

  const int srow = l >> 3;
  const int scol = ((l & 7) * 16) ^ ((srow & 7) << 4);
  #pragma unroll
  for (int it = 0; it < 2; ++it) {
    int rbase = w * 16 + it * 8;
    gload_lds16(KC  + (size_t)bh * 4096 + (rbase + srow) * 64 + (scol >> 1), &Klds[rbase * 64]);
    gload_lds16(VCT + (size_t)bh * 4096 + (rbase + srow) * 64 + (scol >> 1), &Vlds[rbase * 64]);
  }
  if (tid < 64) svb[tid] = vbias[bh * TOPK + tid];

  bf16x8 qf0, qf1;
  {
    const unsigned short* qrow =
        Qb + ((size_t)(b * LQ + q0 + w * 16 + lq)) * DD + h * DH + g * 8;
    qf0 = *reinterpret_cast<const bf16x8*>(qrow);
    qf1 = *reinterpret_cast<const bf16x8*>(qrow + 32);
  }
  __syncthreads();

  f32x4 S[4];
  #pragma unroll
  for (int kt = 0; kt < 4; ++kt) {
    f32x4 acc = {};
    int row = kt * 16 + lq;
    int c0 = (g * 16) ^ ((row & 7) << 4);
    int c1 = (64 + g * 16) ^ ((row & 7) << 4);
    bf16x8 a0 = *reinterpret_cast<const bf16x8*>(&Klds[row * 64 + (c0 >> 1)]);
    bf16x8 a1 = *reinterpret_cast<const bf16x8*>(&Klds[row * 64 + (c1 >> 1)]);
    acc = __builtin_amdgcn_mfma_f32_16x16x32_bf16(a0, qf0, acc, 0, 0, 0);
    acc = __builtin_amdgcn_mfma_f32_16x16x32_bf16(a1, qf1, acc, 0, 0, 0);
    S[kt] = acc;
  }

  float s_v[16];
  float mx = -INFINITY;
  #pragma unroll
  for (int kt = 0; kt < 4; ++kt)
    #pragma unroll
    for (int r = 0; r < 4; ++r) {
      float s = S[kt][r] + svb[kt * 16 + g * 4 + r];
      s_v[kt * 4 + r] = s;
      mx = fmaxf(mx, s);
    }
  mx = fmaxf(mx, __shfl_xor(mx, 16));
  mx = fmaxf(mx, __shfl_xor(mx, 32));
  float nd = ndv[bh];
  float m2 = (nd > 0.0f) ? fmaxf(mx, 0.0f) : mx;

  float psum = 0.0f;
  unsigned short pb[16];
  #pragma unroll
  for (int i = 0; i < 16; ++i) {
    float p = __expf(s_v[i] - m2);
    psum += p;
    pb[i] = f2bf(p);
  }
  psum += __shfl_xor(psum, 16);
  psum += __shfl_xor(psum, 32);
  float Z = psum + nd * __expf(-m2);
  float inv = 1.0f / Z;

  bf16x8 pa0, pa1;
  #pragma unroll
  for (int j = 0; j < 8; ++j) { pa0[j] = (short)pb[j]; pa1[j] = (short)pb[8 + j]; }

  f32x4 O[4] = {};
  #pragma unroll
  for (int dt = 0; dt < 4; ++dt) {
    int r = dt * 16 + lq;
    int swz = (r & 7) << 4;
    #pragma unroll
    for (int ks = 0; ks < 2; ++ks) {
      int cl = (64 * ks + g * 8) ^ swz;
      int ch = (64 * ks + 32 + g * 8) ^ swz;
      u16x4 lo = *reinterpret_cast<const u16x4*>(&Vlds[r * 64 + (cl >> 1)]);
      u16x4 hi = *reinterpret_cast<const u16x4*>(&Vlds[r * 64 + (ch >> 1)]);
      bf16x8 vb = { (short)lo[0], (short)lo[1], (short)lo[2], (short)lo[3],
                    (short)hi[0], (short)hi[1], (short)hi[2], (short)hi[3] };
      O[dt] = __builtin_amdgcn_mfma_f32_16x16x32_bf16(ks == 0 ? pa0 : pa1, vb, O[dt], 0, 0, 0);
    }
  }

  float invl[4];
  #pragma unroll
  for (int r = 0; r < 4; ++r) invl[r] = __shfl(inv, g * 4 + r);
  float gh = g_h[bh];
  #pragma unroll
  for (int dt = 0; dt < 4; ++dt)
    #pragma unroll
    for (int r = 0; r < 4; ++r) {
      int q = q0 + w * 16 + g * 4 + r;
      att[((size_t)(b * LQ + q)) * DD + h * DH + dt * 16 + lq] =
          f2bf(O[dt][r] * invl[r] * gh);
    }
}

extern "C" void kernel_launch(void* const* d_in, const int* in_sizes, int n_in,
                              void* d_out, int out_size, void* d_ws, size_t ws_size,
                              hipStream_t stream) {
  const float* x_q      = (const float*)d_in[0];
  const float* x_kv     = (const float*)d_in[1];
  const int*   mask     = (const int*)d_in[2];
  const float* wq       = (const float*)d_in[3];
  const float* wk       = (const float*)d_in[4];
  const float* wv       = (const float*)d_in[5];
  const float* wo       = (const float*)d_in[6];
  const float* ln_q_g   = (const float*)d_in[7];
  const float* ln_q_b   = (const float*)d_in[8];
  const float* ln_kv_g  = (const float*)d_in[9];
  const float* ln_kv_b  = (const float*)d_in[10];
  const float* hq       = (const float*)d_in[11];
  const float* resid_l  = (const float*)d_in[12];
  float* out = (float*)d_out;
  float* ws  = (float*)d_ws;

  unsigned short* xqb  = (unsigned short*)(ws + XQBF);
  unsigned short* xkvb = (unsigned short*)(ws + XKVBF);
  unsigned short* wqb  = (unsigned short*)(ws + WQB);
  unsigned short* wkb  = (unsigned short*)(ws + WKB);
  unsigned short* wvb  = (unsigned short*)(ws + WVB);
  unsigned short* wob  = (unsigned short*)(ws + WOB);
  unsigned short* QBF  = (unsigned short*)(ws + QBFo);
  float*          GS   = (float*)(ws + GSo);
  float*          UF   = (float*)(ws + UFo);
  int*            IDX  = (int*)(ws + IDXo);
  unsigned short* KC   = (unsigned short*)(ws + KCo);
  unsigned short* VCT  = (unsigned short*)(ws + VCTo);
  unsigned short* ABF  = xqb;   // reuse xq_n slot after Q-GEMM

  conv4u<<<dim3(576, 5), dim3(256), 0, stream>>>(wq, wk, wv, wo, wqb, wkb, wvb, wob, hq, UF);

  ln_all<<<dim3(BB * LQ + BB * LT), dim3(256), 0, stream>>>(x_q, x_kv, ln_q_g, ln_q_b,
                                                            ln_kv_g, ln_kv_b, xqb, xkvb, UF, GS);

  gate_topk<<<dim3(BB * HH), dim3(512), 0, stream>>>(GS, mask, IDX,
                                                     ws + VBIA, ws + NDVo, ws + GHo);

  proj2<<<dim3(624), dim3(256), 0, stream>>>(xqb, wqb, xkvb, wkb, wvb, IDX, QBF, KC, VCT);

  attn_topk<<<dim3(LQ / 64, BB * HH), dim3(256), 0, stream>>>(QBF, KC, VCT,
                                                              ws + VBIA, ws + NDVo, ws + GHo, ABF);

  o_gemm<<<dim3(432), dim3(256), 0, stream>>>(ABF, wob, out, x_q, resid_l);
}

// Round 15
// 102.956 us; speedup vs baseline: 1.2092x; 1.2092x over previous
//
#include <hip/hip_runtime.h>
#include <math.h>

// Problem constants
#define BB 16
#define LQ 576
#define LT 512
#define DD 768
#define HH 12
#define DH 64
#define TOPK 64

typedef __attribute__((ext_vector_type(8))) short bf16x8;
typedef __attribute__((ext_vector_type(4))) float f32x4;
typedef __attribute__((ext_vector_type(4))) unsigned short u16x4;

// Workspace layout (float offsets)
static constexpr size_t XQBF  = 0;          // 9216*768 bf16 (xq_n; reused as attn-out ABF)
static constexpr size_t XKVBF = 3538944;    // 8192*768 bf16
static constexpr size_t WQB   = 6684672;    // 768*768 bf16
static constexpr size_t WKB   = 6979584;    // wk bf16
static constexpr size_t WVB   = 7274496;    // wv bf16
static constexpr size_t WOB   = 7569408;    // wo bf16
static constexpr size_t QBFo  = 7864320;    // 9216*768 bf16 (pre-scaled by 0.125)
static constexpr size_t UBo   = 11403264;   // 16*768 bf16 (u[h] rows; rows 12..15 zero)
static constexpr size_t GSo   = 11409408;   // 8192*16 f32 gate scores
static constexpr size_t IDXo  = 17694720;   // 192*64 int
static constexpr size_t VBIA  = 17707008;   // 192*64 f32 (0 or -inf)
static constexpr size_t NDVo  = 17719296;   // 192 f32
static constexpr size_t GHo   = 17719488;   // 192 f32
static constexpr size_t KCo   = 17719680;   // 192*64*64 bf16 (kept K, rank order)
static constexpr size_t VCTo  = 18112896;   // 192*64*64 bf16 (V^T compact [d][j])

__device__ inline unsigned short f2bf(float f) {
  union { float f; unsigned u; } v; v.f = f;
  unsigned r = v.u + 0x7FFFu + ((v.u >> 16) & 1u);
  return (unsigned short)(r >> 16);
}
__device__ inline float bf2f(unsigned short u) {
  union { unsigned u; float f; } v; v.u = ((unsigned)u) << 16;
  return v.f;
}
__device__ inline void gload_lds16(const void* src, void* dst) {
  __builtin_amdgcn_global_load_lds((const __attribute__((address_space(1))) void*)src,
                                   (__attribute__((address_space(3))) void*)dst, 16, 0, 0);
}
// compiler-invisible LDS read (no alias edge to outstanding global_load_lds)
__device__ inline bf16x8 lds_read16(const unsigned short* p) {
  bf16x8 r;
  asm volatile("ds_read_b128 %0, %1"
               : "=v"(r)
               : "v"((const __attribute__((address_space(3))) unsigned short*)p));
  return r;
}

// ---------------- LayerNorm -> bf16 (both tensors, one launch) ----------------
__global__ __launch_bounds__(256) void ln_all(const float* __restrict__ xq,
                                              const float* __restrict__ xkv,
                                              const float* __restrict__ gq,
                                              const float* __restrict__ bq,
                                              const float* __restrict__ gkv,
                                              const float* __restrict__ bkv,
                                              unsigned short* __restrict__ yq,
                                              unsigned short* __restrict__ ykv) {
  int row = blockIdx.x;
  const float *xr, *gg, *bb;
  unsigned short* yr;
  if (row < BB * LQ) {
    xr = xq + (size_t)row * DD; gg = gq; bb = bq; yr = yq + (size_t)row * DD;
  } else {
    int r = row - BB * LQ;
    xr = xkv + (size_t)r * DD; gg = gkv; bb = bkv; yr = ykv + (size_t)r * DD;
  }
  int t = threadIdx.x;
  float v0 = xr[t], v1 = xr[t + 256], v2 = xr[t + 512];
  __shared__ float red[4];
  float s = v0 + v1 + v2;
  #pragma unroll
  for (int o = 32; o > 0; o >>= 1) s += __shfl_xor(s, o);
  if ((t & 63) == 0) red[t >> 6] = s;
  __syncthreads();
  float m = (red[0] + red[1] + red[2] + red[3]) * (1.0f / 768.0f);
  float d0 = v0 - m, d1 = v1 - m, d2 = v2 - m;
  float s2 = d0 * d0 + d1 * d1 + d2 * d2;
  #pragma unroll
  for (int o = 32; o > 0; o >>= 1) s2 += __shfl_xor(s2, o);
  __syncthreads();
  if ((t & 63) == 0) red[t >> 6] = s2;
  __syncthreads();
  float var = (red[0] + red[1] + red[2] + red[3]) * (1.0f / 768.0f);
  float rs = rsqrtf(var + 1e-5f);
  yr[t]       = f2bf(d0 * rs * gg[t]       + bb[t]);
  yr[t + 256] = f2bf(d1 * rs * gg[t + 256] + bb[t + 256]);
  yr[t + 512] = f2bf(d2 * rs * gg[t + 512] + bb[t + 512]);
}

// ---------------- weight converts + u[h] precompute (one launch, 5 y-slices) ----------------
__global__ __launch_bounds__(256) void conv4u(const float* __restrict__ s0, const float* __restrict__ s1,
                                              const float* __restrict__ s2, const float* __restrict__ s3,
                                              unsigned short* d0, unsigned short* d1,
                                              unsigned short* d2, unsigned short* d3,
                                              const float* __restrict__ hq,
                                              unsigned short* __restrict__ UB) {
  int t = threadIdx.x;
  if (blockIdx.y == 4) {
    int h = blockIdx.x;
    if (h >= 16) return;
    if (h < HH) {
      float a0 = 0.0f, a1 = 0.0f, a2 = 0.0f;
      for (int d = 0; d < DH; ++d) {
        float sc = hq[h * DH + d];
        const float* wr = s1 + (size_t)(h * DH + d) * DD;
        a0 += sc * wr[t]; a1 += sc * wr[t + 256]; a2 += sc * wr[t + 512];
      }
      UB[h * DD + t]       = f2bf(a0 * 0.125f);
      UB[h * DD + t + 256] = f2bf(a1 * 0.125f);
      UB[h * DD + t + 512] = f2bf(a2 * 0.125f);
    } else {
      UB[h * DD + t] = 0; UB[h * DD + t + 256] = 0; UB[h * DD + t + 512] = 0;
    }
    return;
  }
  const float* s; unsigned short* d;
  switch (blockIdx.y) {
    case 0: s = s0; d = d0; break;
    case 1: s = s1; d = d1; break;
    case 2: s = s2; d = d2; break;
    default: s = s3; d = d3; break;
  }
  int i = (blockIdx.x * 256 + t) * 4;
  float4 v = *reinterpret_cast<const float4*>(&s[i]);
  u16x4 o = { f2bf(v.x), f2bf(v.y), f2bf(v.z), f2bf(v.w) };
  *reinterpret_cast<u16x4*>(&d[i]) = o;
}

// ===== common GEMM machinery (counted-vmcnt 2-phase, T4; asm ds_read) =====

#define COMMON_PREAMBLE()                                                      \
  const int tid = threadIdx.x;                                                 \
  const int w = tid >> 6, l = tid & 63;                                        \
  const int lq = l & 15, g = l >> 4;                                           \
  const int srow = l >> 3;                                                     \
  const int scol = ((l & 7) * 16) ^ ((srow & 7) << 4);

// 8 VMEM per wave per stage (4 A + 4 B); 128x128 tile, BK=64
#define STAGE2(BUFI, T)                                                        \
  {                                                                            \
    int k0s = (T) * 64;                                                        \
    _Pragma("unroll")                                                          \
    for (int it = 0; it < 4; ++it) {                                           \
      int rbase = it * 32 + w * 8;                                             \
      gload_lds16(Asrc + (size_t)rbase * DD + k0s, &As[BUFI][rbase * 64]);     \
      gload_lds16(Bsrc + (size_t)rbase * DD + k0s, &Bs[BUFI][rbase * 64]);     \
    }                                                                          \
  }

#define COMPUTE2(BUFI)                                                         \
  {                                                                            \
    bf16x8 a[4][2], b[4][2];                                                   \
    _Pragma("unroll")                                                          \
    for (int mi = 0; mi < 4; ++mi)                                             \
      _Pragma("unroll")                                                        \
      for (int ks = 0; ks < 2; ++ks) {                                         \
        a[mi][ks] = lds_read16(&As[BUFI][aoff[mi][ks]]);                       \
        b[mi][ks] = lds_read16(&Bs[BUFI][boff[mi][ks]]);                       \
      }                                                                        \
    asm volatile("s_waitcnt lgkmcnt(0)" ::: "memory");                         \
    __builtin_amdgcn_sched_barrier(0);                                         \
    _Pragma("unroll")                                                          \
    for (int ks = 0; ks < 2; ++ks)                                             \
      _Pragma("unroll")                                                        \
      for (int mi = 0; mi < 4; ++mi)                                           \
        _Pragma("unroll")                                                      \
        for (int ni = 0; ni < 4; ++ni)                                         \
          acc[mi][ni] = __builtin_amdgcn_mfma_f32_16x16x32_bf16(               \
              a[mi][ks], b[ni][ks], acc[mi][ni], 0, 0, 0);                     \
  }

#define GEMM_MAIN()                                                            \
  int aoff[4][2], boff[4][2];                                                  \
  _Pragma("unroll")                                                            \
  for (int mi = 0; mi < 4; ++mi) {                                             \
    int rowa = wr * 64 + mi * 16 + lq;                                         \
    int rowb = wc * 64 + mi * 16 + lq;                                         \
    _Pragma("unroll")                                                          \
    for (int ks = 0; ks < 2; ++ks) {                                           \
      aoff[mi][ks] = rowa * 64 + (((ks * 64 + g * 16) ^ ((rowa & 7) << 4)) >> 1); \
      boff[mi][ks] = rowb * 64 + (((ks * 64 + g * 16) ^ ((rowb & 7) << 4)) >> 1); \
    }                                                                          \
  }                                                                            \
  STAGE2(0, 0);                                                                \
  STAGE2(1, 1);                                                                \
  _Pragma("unroll")                                                            \
  for (int t = 0; t < 12; ++t) {                                               \
    if (t < 11) asm volatile("s_waitcnt vmcnt(8)" ::: "memory");               \
    else        asm volatile("s_waitcnt vmcnt(0)" ::: "memory");               \
    __builtin_amdgcn_sched_barrier(0);                                         \
    __builtin_amdgcn_s_barrier();                                              \
    if ((t & 1) == 0) { COMPUTE2(0); } else { COMPUTE2(1); }                   \
    __builtin_amdgcn_s_barrier();                                              \
    __builtin_amdgcn_sched_barrier(0);                                         \
    if (t + 2 < 12) {                                                          \
      if ((t & 1) == 0) { STAGE2(0, t + 2); } else { STAGE2(1, t + 2); }       \
    }                                                                          \
  }

// ---------------- gate-score GEMM: GS[8192,16] = xkv_n * U^T ----------------
__global__ __launch_bounds__(256) void gs_gemm(const unsigned short* __restrict__ xkvb,
                                               const unsigned short* __restrict__ UB,
                                               float* __restrict__ GS) {
  __shared__ __align__(16) unsigned short Xs[2][64 * 64];
  __shared__ __align__(16) unsigned short Us[2][16 * 64];
  COMMON_PREAMBLE();
  const int bm = blockIdx.x * 64;
  const unsigned short* Asrc = xkvb + (size_t)(bm + srow) * DD + (scol >> 1);
  const unsigned short* Us0 = UB + (size_t)srow * DD + (scol >> 1);
  const unsigned short* Us1 = UB + (size_t)(8 + srow) * DD + (scol >> 1);

#define GS_STAGE(BUFI, T)                                                      \
  {                                                                            \
    int k0s = (T) * 64;                                                        \
    _Pragma("unroll")                                                          \
    for (int it = 0; it < 2; ++it) {                                           \
      int rbase = it * 32 + w * 8;                                             \
      gload_lds16(Asrc + (size_t)rbase * DD + k0s, &Xs[BUFI][rbase * 64]);     \
    }                                                                          \
    gload_lds16(Us0 + k0s, &Us[BUFI][0]);                                      \
    gload_lds16(Us1 + k0s, &Us[BUFI][8 * 64]);                                 \
  }

  f32x4 acc = {};

#define GS_COMPUTE(BUFI)                                                       \
  {                                                                            \
    bf16x8 a[2], b[2];                                                         \
    _Pragma("unroll")                                                          \
    for (int ks = 0; ks < 2; ++ks) {                                           \
      int arow = w * 16 + lq;                                                  \
      int acb = (ks * 64 + g * 16) ^ ((arow & 7) << 4);                        \
      a[ks] = lds_read16(&Xs[BUFI][arow * 64 + (acb >> 1)]);                   \
      int brow = lq;                                                           \
      int bcb = (ks * 64 + g * 16) ^ ((brow & 7) << 4);                        \
      b[ks] = lds_read16(&Us[BUFI][brow * 64 + (bcb >> 1)]);                   \
    }                                                                          \
    asm volatile("s_waitcnt lgkmcnt(0)" ::: "memory");                         \
    __builtin_amdgcn_sched_barrier(0);                                         \
    _Pragma("unroll")                                                          \
    for (int ks = 0; ks < 2; ++ks)                                             \
      acc = __builtin_amdgcn_mfma_f32_16x16x32_bf16(a[ks], b[ks], acc, 0, 0, 0); \
  }

  GS_STAGE(0, 0);
  GS_STAGE(1, 1);
  #pragma unroll
  for (int t = 0; t < 12; ++t) {
    if (t < 11) asm volatile("s_waitcnt vmcnt(4)" ::: "memory");
    else        asm volatile("s_waitcnt vmcnt(0)" ::: "memory");
    __builtin_amdgcn_sched_barrier(0);
    __builtin_amdgcn_s_barrier();
    if ((t & 1) == 0) { GS_COMPUTE(0); } else { GS_COMPUTE(1); }
    __builtin_amdgcn_s_barrier();
    __builtin_amdgcn_sched_barrier(0);
    if (t + 2 < 12) {
      if ((t & 1) == 0) { GS_STAGE(0, t + 2); } else { GS_STAGE(1, t + 2); }
    }
  }
  #pragma unroll
  for (int r = 0; r < 4; ++r)
    GS[(size_t)(bm + w * 16 + g * 4 + r) * 16 + lq] = acc[r];
}

// ---------------- Gate + top-k (scores precomputed; g = sum p*s) ----------------
__global__ __launch_bounds__(512) void gate_topk(const float* __restrict__ GS,
                                                 const int* __restrict__ mask,
                                                 int* __restrict__ idxo,
                                                 float* __restrict__ vbias,
                                                 float* __restrict__ ndv,
                                                 float* __restrict__ g_h) {
  int bh = blockIdx.x, b = bh / HH, h = bh % HH;
  int l = threadIdx.x;
  __shared__ float s_sc[512];
  __shared__ float red[8];
  __shared__ int wred[8];
  float sc = GS[(size_t)(b * LT + l) * 16 + h];
  bool maskv = (mask[b * LT + l] != 0);
  if (!maskv) sc = -INFINITY;
  s_sc[l] = sc;
  float m0 = sc;
  #pragma unroll
  for (int o = 32; o > 0; o >>= 1) m0 = fmaxf(m0, __shfl_xor(m0, o));
  if ((l & 63) == 0) red[l >> 6] = m0;
  __syncthreads();
  float m = red[0];
  #pragma unroll
  for (int w = 1; w < 8; w++) m = fmaxf(m, red[w]);
  float p = __expf(sc - m);
  float s1 = p;
  #pragma unroll
  for (int o = 32; o > 0; o >>= 1) s1 += __shfl_xor(s1, o);
  __syncthreads();
  if ((l & 63) == 0) red[l >> 6] = s1;
  __syncthreads();
  float Z = 0.0f;
  #pragma unroll
  for (int w = 0; w < 8; w++) Z += red[w];
  p /= Z;
  float gc = maskv ? p * sc : 0.0f;
  #pragma unroll
  for (int o = 32; o > 0; o >>= 1) gc += __shfl_xor(gc, o);
  __syncthreads();
  if ((l & 63) == 0) red[l >> 6] = gc;
  __syncthreads();
  if (l == 0) {
    float G = 0.0f;
    #pragma unroll
    for (int w = 0; w < 8; w++) G += red[w];
    g_h[bh] = 1.0f / (1.0f + __expf(-G));
  }
  float my = s_sc[l];
  int cnt = 0;
  for (int j = 0; j < LT; j++) {
    float sj = s_sc[j];
    cnt += (sj > my || (sj == my && j < l)) ? 1 : 0;
  }
  if (cnt < TOPK) {
    idxo[bh * TOPK + cnt] = l;
    vbias[bh * TOPK + cnt] = maskv ? 0.0f : -INFINITY;
  }
  int dv = (maskv && cnt >= TOPK) ? 1 : 0;
  unsigned long long bal = __ballot(dv);
  if ((l & 63) == 0) wred[l >> 6] = __popcll(bal);
  __syncthreads();
  if (l == 0) {
    int nd = 0;
    #pragma unroll
    for (int w = 0; w < 8; w++) nd += wred[w];
    ndv[bh] = (float)nd;
  }
}

// ---------------- fused: Q projection (432 blocks) + compact K&V gather-GEMM (192 blocks) ----------------
__global__ __launch_bounds__(256, 2) void proj2(const unsigned short* __restrict__ xqb,
                                                const unsigned short* __restrict__ wqb,
                                                const unsigned short* __restrict__ xkvb,
                                                const unsigned short* __restrict__ wkb,
                                                const unsigned short* __restrict__ wvb,
                                                const int* __restrict__ idxo,
                                                unsigned short* __restrict__ QBF,
                                                unsigned short* __restrict__ KC,
                                                unsigned short* __restrict__ VCT) {
  __shared__ __align__(16) unsigned short As[2][128 * 64];
  __shared__ __align__(16) unsigned short Bs[2][128 * 64];
  __shared__ int sidx[64];
  COMMON_PREAMBLE();
  int p = blockIdx.x;                       // 624 = 8 * 78
  int bid = (p & 7) * 78 + (p >> 3);

  if (bid < 432) {
    // ---- Q projection, 128x128 tile ----
    const int wr = w >> 1, wc = w & 1;
    const int mtile = bid / 6, nt = bid % 6;
    const int bm = mtile * 128, bn = nt * 128;
    const unsigned short* Asrc = xqb + (size_t)(bm + srow) * DD + (scol >> 1);
    const unsigned short* Bsrc = wqb + (size_t)(bn + srow) * DD + (scol >> 1);
    f32x4 acc[4][4] = {};
    GEMM_MAIN();
    const int m_base = bm + wr * 64, n_base = bn + wc * 64;
    #pragma unroll
    for (int mi = 0; mi < 4; ++mi)
      #pragma unroll
      for (int r = 0; r < 4; ++r) {
        int m = m_base + mi * 16 + g * 4 + r;
        #pragma unroll
        for (int ni = 0; ni < 4; ++ni) {
          int n = n_base + ni * 16 + lq;
          QBF[(size_t)m * DD + n] = f2bf(acc[mi][ni][r] * 0.125f);
        }
      }
  } else {
    // ---- compact K & V: per (b,h), Kc[j,d] / Vct[d,j], 64x64x768 gather-GEMM ----
    const int bh = bid - 432, b = bh / HH, h = bh % HH;
    if (tid < 64) sidx[tid] = idxo[bh * TOPK + tid];
    __syncthreads();
    unsigned short* Xs0 = &As[0][0]; unsigned short* Xs1 = &As[0][4096];
    unsigned short* Kp0 = &As[1][0]; unsigned short* Kp1 = &As[1][4096];
    unsigned short* Vp0 = &Bs[0][0]; unsigned short* Vp1 = &Bs[0][4096];
    const int j0 = w * 16 + srow, j1 = w * 16 + 8 + srow;
    const unsigned short* xs0 = xkvb + (size_t)(b * LT + sidx[j0]) * DD + (scol >> 1);
    const unsigned short* xs1 = xkvb + (size_t)(b * LT + sidx[j1]) * DD + (scol >> 1);
    const unsigned short* wk0 = wkb + (size_t)(h * DH + j0) * DD + (scol >> 1);
    const unsigned short* wk1 = wkb + (size_t)(h * DH + j1) * DD + (scol >> 1);
    const unsigned short* wv0 = wvb + (size_t)(h * DH + j0) * DD + (scol >> 1);
    const unsigned short* wv1 = wvb + (size_t)(h * DH + j1) * DD + (scol >> 1);

#define KV_STAGE(Xd, Kd, Vd, T)                                                \
    {                                                                          \
      int k0s = (T) * 64;                                                      \
      gload_lds16(xs0 + k0s, Xd + (w * 16) * 64);                              \
      gload_lds16(xs1 + k0s, Xd + (w * 16 + 8) * 64);                          \
      gload_lds16(wk0 + k0s, Kd + (w * 16) * 64);                              \
      gload_lds16(wk1 + k0s, Kd + (w * 16 + 8) * 64);                          \
      gload_lds16(wv0 + k0s, Vd + (w * 16) * 64);                              \
      gload_lds16(wv1 + k0s, Vd + (w * 16 + 8) * 64);                          \
    }

    f32x4 accK[4] = {}, accV[4] = {};

#define KV_COMPUTE(Xd, Kd, Vd)                                                 \
    {                                                                          \
      bf16x8 ax[2], av[2], bk[4][2], bx[4][2];                                 \
      _Pragma("unroll")                                                        \
      for (int ks = 0; ks < 2; ++ks) {                                         \
        int arow = w * 16 + lq;                                                \
        int acb = (ks * 64 + g * 16) ^ ((arow & 7) << 4);                      \
        ax[ks] = lds_read16(Xd + arow * 64 + (acb >> 1));                      \
        av[ks] = lds_read16(Vd + arow * 64 + (acb >> 1));                      \
        _Pragma("unroll")                                                      \
        for (int ni = 0; ni < 4; ++ni) {                                       \
          int brow = ni * 16 + lq;                                             \
          int bcb = (ks * 64 + g * 16) ^ ((brow & 7) << 4);                    \
          bk[ni][ks] = lds_read16(Kd + brow * 64 + (bcb >> 1));                \
          bx[ni][ks] = lds_read16(Xd + brow * 64 + (bcb >> 1));                \
        }                                                                      \
      }                                                                        \
      asm volatile("s_waitcnt lgkmcnt(0)" ::: "memory");                       \
      __builtin_amdgcn_sched_barrier(0);                                       \
      _Pragma("unroll")                                                        \
      for (int ks = 0; ks < 2; ++ks)                                           \
        _Pragma("unroll")                                                      \
        for (int ni = 0; ni < 4; ++ni) {                                       \
          accK[ni] = __builtin_amdgcn_mfma_f32_16x16x32_bf16(ax[ks], bk[ni][ks], accK[ni], 0, 0, 0); \
          accV[ni] = __builtin_amdgcn_mfma_f32_16x16x32_bf16(av[ks], bx[ni][ks], accV[ni], 0, 0, 0); \
        }                                                                      \
    }

    KV_STAGE(Xs0, Kp0, Vp0, 0);
    KV_STAGE(Xs1, Kp1, Vp1, 1);
    #pragma unroll
    for (int t = 0; t < 12; ++t) {
      if (t < 11) asm volatile("s_waitcnt vmcnt(6)" ::: "memory");
      else        asm volatile("s_waitcnt vmcnt(0)" ::: "memory");
      __builtin_amdgcn_sched_barrier(0);
      __builtin_amdgcn_s_barrier();
      if ((t & 1) == 0) { KV_COMPUTE(Xs0, Kp0, Vp0); } else { KV_COMPUTE(Xs1, Kp1, Vp1); }
      __builtin_amdgcn_s_barrier();
      __builtin_amdgcn_sched_barrier(0);
      if (t + 2 < 12) {
        if ((t & 1) == 0) { KV_STAGE(Xs0, Kp0, Vp0, t + 2); } else { KV_STAGE(Xs1, Kp1, Vp1, t + 2); }
      }
    }
    #pragma unroll
    for (int ni = 0; ni < 4; ++ni)
      #pragma unroll
      for (int r = 0; r < 4; ++r) {
        int mrow = w * 16 + g * 4 + r;
        KC [(size_t)bh * 4096 + mrow * 64 + ni * 16 + lq] = f2bf(accK[ni][r]);
        VCT[(size_t)bh * 4096 + mrow * 64 + ni * 16 + lq] = f2bf(accV[ni][r]);
      }
  }
}

// ---------------- output projection GEMM + residual epilogue ----------------
__global__ __launch_bounds__(256, 2) void o_gemm(const unsigned short* __restrict__ ABF,
                                                 const unsigned short* __restrict__ wob,
                                                 float* __restrict__ out,
                                                 const float* __restrict__ resid,
                                                 const float* __restrict__ gl) {
  __shared__ __align__(16) unsigned short As[2][128 * 64];
  __shared__ __align__(16) unsigned short Bs[2][128 * 64];
  COMMON_PREAMBLE();
  const int wr = w >> 1, wc = w & 1;
  int p = blockIdx.x;                     // 432 = 8 * 54
  int bid = (p & 7) * 54 + (p >> 3);
  const int mtile = bid / 6, nt = bid % 6;
  const int bm = mtile * 128, bn = nt * 128;
  const unsigned short* Asrc = ABF + (size_t)(bm + srow) * DD + (scol >> 1);
  const unsigned short* Bsrc = wob + (size_t)(bn + srow) * DD + (scol >> 1);

  f32x4 acc[4][4] = {};
  GEMM_MAIN();

  float alpha = 1.0f / (1.0f + __expf(-gl[0]));
  const int m_base = bm + wr * 64, n_base = bn + wc * 64;
  #pragma unroll
  for (int mi = 0; mi < 4; ++mi)
    #pragma unroll
    for (int r = 0; r < 4; ++r) {
      int m = m_base + mi * 16 + g * 4 + r;
      #pragma unroll
      for (int ni = 0; ni < 4; ++ni) {
        int n = n_base + ni * 16 + lq;
        out[(size_t)m * DD + n] = resid[(size_t)m * DD + n] + alpha * acc[mi][ni][r];
      }
    }
}

// ---------------- Top-k attention: single 64-key tile, closed-form dropped-mass correction ----------------
__global__ __launch_bounds__(256) void attn_topk(const unsigned short* __restrict__ Qb,
                                                 const unsigned short* __restrict__ KC,
                                                 const unsigned short* __restrict__ VCT,
                                                 const float* __restrict__ vbias,
                                                 const float* __restrict__ ndv,
                                                 const float* __restrict__ g_h,
                                                 unsigned short* __restrict__ att) {
  const int bh = blockIdx.y, b = bh / HH, h = bh % HH;
  const int q0 = blockIdx.x * 64;
  const int tid = threadIdx.x;
  const int w = tid >> 6, l = tid & 63;
  const int lq = l & 15, g = l >> 4;

  __shared__ __align__(16) unsigned short Klds[64 * 64];
  __shared__ __align__(16) unsigned short Vlds[64 * 64];
  __shared__ float svb[64];

  const int srow = l >> 3;
  const int scol = ((l & 7) * 16) ^ ((srow & 7) << 4);
  #pragma unroll
  for (int it = 0; it < 2; ++it) {
    int rbase = w * 16 + it * 8;
    gload_lds16(KC  + (size_t)bh * 4096 + (rbase + srow) * 64 + (scol >> 1), &Klds[rbase * 64]);
    gload_lds16(VCT + (size_t)bh * 4096 + (rbase + srow) * 64 + (scol >> 1), &Vlds[rbase * 64]);
  }
  if (tid < 64) svb[tid] = vbias[bh * TOPK + tid];

  bf16x8 qf0, qf1;
  {
    const unsigned short* qrow =
        Qb + ((size_t)(b * LQ + q0 + w * 16 + lq)) * DD + h * DH + g * 8;
    qf0 = *reinterpret_cast<const bf16x8*>(qrow);
    qf1 = *reinterpret_cast<const bf16x8*>(qrow + 32);
  }
  __syncthreads();

  f32x4 S[4];
  #pragma unroll
  for (int kt = 0; kt < 4; ++kt) {
    f32x4 acc = {};
    int row = kt * 16 + lq;
    int c0 = (g * 16) ^ ((row & 7) << 4);
    int c1 = (64 + g * 16) ^ ((row & 7) << 4);
    bf16x8 a0 = *reinterpret_cast<const bf16x8*>(&Klds[row * 64 + (c0 >> 1)]);
    bf16x8 a1 = *reinterpret_cast<const bf16x8*>(&Klds[row * 64 + (c1 >> 1)]);
    acc = __builtin_amdgcn_mfma_f32_16x16x32_bf16(a0, qf0, acc, 0, 0, 0);
    acc = __builtin_amdgcn_mfma_f32_16x16x32_bf16(a1, qf1, acc, 0, 0, 0);
    S[kt] = acc;
  }

  float s_v[16];
  float mx = -INFINITY;
  #pragma unroll
  for (int kt = 0; kt < 4; ++kt)
    #pragma unroll
    for (int r = 0; r < 4; ++r) {
      float s = S[kt][r] + svb[kt * 16 + g * 4 + r];
      s_v[kt * 4 + r] = s;
      mx = fmaxf(mx, s);
    }
  mx = fmaxf(mx, __shfl_xor(mx, 16));
  mx = fmaxf(mx, __shfl_xor(mx, 32));
  float nd = ndv[bh];
  float m2 = (nd > 0.0f) ? fmaxf(mx, 0.0f) : mx;

  float psum = 0.0f;
  unsigned short pb[16];
  #pragma unroll
  for (int i = 0; i < 16; ++i) {
    float p = __expf(s_v[i] - m2);
    psum += p;
    pb[i] = f2bf(p);
  }
  psum += __shfl_xor(psum, 16);
  psum += __shfl_xor(psum, 32);
  float Z = psum + nd * __expf(-m2);
  float inv = 1.0f / Z;

  bf16x8 pa0, pa1;
  #pragma unroll
  for (int j = 0; j < 8; ++j) { pa0[j] = (short)pb[j]; pa1[j] = (short)pb[8 + j]; }

  f32x4 O[4] = {};
  #pragma unroll
  for (int dt = 0; dt < 4; ++dt) {
    int r = dt * 16 + lq;
    int swz = (r & 7) << 4;
    #pragma unroll
    for (int ks = 0; ks < 2; ++ks) {
      int cl = (64 * ks + g * 8) ^ swz;
      int ch = (64 * ks + 32 + g * 8) ^ swz;
      u16x4 lo = *reinterpret_cast<const u16x4*>(&Vlds[r * 64 + (cl >> 1)]);
      u16x4 hi = *reinterpret_cast<const u16x4*>(&Vlds[r * 64 + (ch >> 1)]);
      bf16x8 vb = { (short)lo[0], (short)lo[1], (short)lo[2], (short)lo[3],
                    (short)hi[0], (short)hi[1], (short)hi[2], (short)hi[3] };
      O[dt] = __builtin_amdgcn_mfma_f32_16x16x32_bf16(ks == 0 ? pa0 : pa1, vb, O[dt], 0, 0, 0);
    }
  }

  float invl[4];
  #pragma unroll
  for (int r = 0; r < 4; ++r) invl[r] = __shfl(inv, g * 4 + r);
  float gh = g_h[bh];
  #pragma unroll
  for (int dt = 0; dt < 4; ++dt)
    #pragma unroll
    for (int r = 0; r < 4; ++r) {
      int q = q0 + w * 16 + g * 4 + r;
      att[((size_t)(b * LQ + q)) * DD + h * DH + dt * 16 + lq] =
          f2bf(O[dt][r] * invl[r] * gh);
    }
}

extern "C" void kernel_launch(void* const* d_in, const int* in_sizes, int n_in,
                              void* d_out, int out_size, void* d_ws, size_t ws_size,
                              hipStream_t stream) {
  const float* x_q      = (const float*)d_in[0];
  const float* x_kv     = (const float*)d_in[1];
  const int*   mask     = (const int*)d_in[2];
  const float* wq       = (const float*)d_in[3];
  const float* wk       = (const float*)d_in[4];
  const float* wv       = (const float*)d_in[5];
  const float* wo       = (const float*)d_in[6];
  const float* ln_q_g   = (const float*)d_in[7];
  const float* ln_q_b   = (const float*)d_in[8];
  const float* ln_kv_g  = (const float*)d_in[9];
  const float* ln_kv_b  = (const float*)d_in[10];
  const float* hq       = (const float*)d_in[11];
  const float* resid_l  = (const float*)d_in[12];
  float* out = (float*)d_out;
  float* ws  = (float*)d_ws;

  unsigned short* xqb  = (unsigned short*)(ws + XQBF);
  unsigned short* xkvb = (unsigned short*)(ws + XKVBF);
  unsigned short* wqb  = (unsigned short*)(ws + WQB);
  unsigned short* wkb  = (unsigned short*)(ws + WKB);
  unsigned short* wvb  = (unsigned short*)(ws + WVB);
  unsigned short* wob  = (unsigned short*)(ws + WOB);
  unsigned short* QBF  = (unsigned short*)(ws + QBFo);
  unsigned short* UB   = (unsigned short*)(ws + UBo);
  float*          GS   = (float*)(ws + GSo);
  int*            IDX  = (int*)(ws + IDXo);
  unsigned short* KC   = (unsigned short*)(ws + KCo);
  unsigned short* VCT  = (unsigned short*)(ws + VCTo);
  unsigned short* ABF  = xqb;   // reuse xq_n slot after Q-GEMM

  conv4u<<<dim3(576, 5), dim3(256), 0, stream>>>(wq, wk, wv, wo, wqb, wkb, wvb, wob, hq, UB);

  ln_all<<<dim3(BB * LQ + BB * LT), dim3(256), 0, stream>>>(x_q, x_kv, ln_q_g, ln_q_b,
                                                            ln_kv_g, ln_kv_b, xqb, xkvb);

  gs_gemm<<<dim3(128), dim3(256), 0, stream>>>(xkvb, UB, GS);

  gate_topk<<<dim3(BB * HH), dim3(512), 0, stream>>>(GS, mask, IDX,
                                                     ws + VBIA, ws + NDVo, ws + GHo);

  proj2<<<dim3(624), dim3(256), 0, stream>>>(xqb, wqb, xkvb, wkb, wvb, IDX, QBF, KC, VCT);

  attn_topk<<<dim3(LQ / 64, BB * HH), dim3(256), 0, stream>>>(QBF, KC, VCT,
                                                              ws + VBIA, ws + NDVo, ws + GHo, ABF);

  o_gemm<<<dim3(432), dim3(256), 0, stream>>>(ABF, wob, out, x_q, resid_l);
}

// Round 17
// 99.710 us; speedup vs baseline: 1.2485x; 1.0326x over previous
//
#include <hip/hip_runtime.h>
#include <math.h>

// Problem constants
#define BB 16
#define LQ 576
#define LT 512
#define DD 768
#define HH 12
#define DH 64
#define TOPK 64

typedef __attribute__((ext_vector_type(8))) short bf16x8;
typedef __attribute__((ext_vector_type(4))) float f32x4;
typedef __attribute__((ext_vector_type(4))) unsigned short u16x4;

// Workspace layout (float offsets)
static constexpr size_t XQBF  = 0;          // 9216*768 bf16 (xq_n; reused as attn-out ABF)
static constexpr size_t XKVBF = 3538944;    // 8192*768 bf16
static constexpr size_t WQB   = 6684672;    // 768*768 bf16
static constexpr size_t WKB   = 6979584;    // wk bf16
static constexpr size_t WVB   = 7274496;    // wv bf16
static constexpr size_t WOB   = 7569408;    // wo bf16
static constexpr size_t QBFo  = 7864320;    // 9216*768 bf16 (pre-scaled by 0.125)
static constexpr size_t UBo   = 11403264;   // 16*768 bf16 (u[h] rows; rows 12..15 zero)
static constexpr size_t GSo   = 11409408;   // 8192*16 f32 gate scores
static constexpr size_t IDXo  = 17694720;   // 192*64 int
static constexpr size_t VBIA  = 17707008;   // 192*64 f32 (0 or -inf)
static constexpr size_t NDVo  = 17719296;   // 192 f32
static constexpr size_t GHo   = 17719488;   // 192 f32
static constexpr size_t KCo   = 17719680;   // 192*64*64 bf16 (kept K, rank order)
static constexpr size_t VCTo  = 18112896;   // 192*64*64 bf16 (V^T compact [d][j])

__device__ inline unsigned short f2bf(float f) {
  union { float f; unsigned u; } v; v.f = f;
  unsigned r = v.u + 0x7FFFu + ((v.u >> 16) & 1u);
  return (unsigned short)(r >> 16);
}
__device__ inline float bf2f(unsigned short u) {
  union { unsigned u; float f; } v; v.u = ((unsigned)u) << 16;
  return v.f;
}
__device__ inline void gload_lds16(const void* src, void* dst) {
  __builtin_amdgcn_global_load_lds((const __attribute__((address_space(1))) void*)src,
                                   (__attribute__((address_space(3))) void*)dst, 16, 0, 0);
}
// compiler-invisible LDS read (no alias edge to outstanding global_load_lds)
__device__ inline bf16x8 lds_read16(const unsigned short* p) {
  bf16x8 r;
  asm volatile("ds_read_b128 %0, %1"
               : "=v"(r)
               : "v"((const __attribute__((address_space(3))) unsigned short*)p));
  return r;
}

// ---------------- fused: LayerNorm (both tensors) + weight converts + u precompute ----------------
// blockIdx.x < 17408: LN rows. Else 2880 conv blocks (5 slices of 576).
__global__ __launch_bounds__(256) void ln_conv(const float* __restrict__ xq,
                                               const float* __restrict__ xkv,
                                               const float* __restrict__ gq,
                                               const float* __restrict__ bq,
                                               const float* __restrict__ gkv,
                                               const float* __restrict__ bkv,
                                               unsigned short* __restrict__ yq,
                                               unsigned short* __restrict__ ykv,
                                               const float* __restrict__ s0,
                                               const float* __restrict__ s1,
                                               const float* __restrict__ s2,
                                               const float* __restrict__ s3,
                                               unsigned short* d0, unsigned short* d1,
                                               unsigned short* d2, unsigned short* d3,
                                               const float* __restrict__ hq,
                                               unsigned short* __restrict__ UB) {
  int row = blockIdx.x;
  int t = threadIdx.x;
  if (row >= BB * LQ + BB * LT) {
    // ---- conv / u-precompute part ----
    int c = row - (BB * LQ + BB * LT);
    int cy = c / 576, cx = c % 576;
    if (cy == 4) {
      int h = cx;
      if (h >= 16) return;
      if (h < HH) {
        float a0 = 0.0f, a1 = 0.0f, a2 = 0.0f;
        for (int d = 0; d < DH; ++d) {
          float sc = hq[h * DH + d];
          const float* wr = s1 + (size_t)(h * DH + d) * DD;
          a0 += sc * wr[t]; a1 += sc * wr[t + 256]; a2 += sc * wr[t + 512];
        }
        UB[h * DD + t]       = f2bf(a0 * 0.125f);
        UB[h * DD + t + 256] = f2bf(a1 * 0.125f);
        UB[h * DD + t + 512] = f2bf(a2 * 0.125f);
      } else {
        UB[h * DD + t] = 0; UB[h * DD + t + 256] = 0; UB[h * DD + t + 512] = 0;
      }
      return;
    }
    const float* s; unsigned short* d;
    switch (cy) {
      case 0: s = s0; d = d0; break;
      case 1: s = s1; d = d1; break;
      case 2: s = s2; d = d2; break;
      default: s = s3; d = d3; break;
    }
    int i = (cx * 256 + t) * 4;
    float4 v = *reinterpret_cast<const float4*>(&s[i]);
    u16x4 o = { f2bf(v.x), f2bf(v.y), f2bf(v.z), f2bf(v.w) };
    *reinterpret_cast<u16x4*>(&d[i]) = o;
    return;
  }
  // ---- LN part ----
  const float *xr, *gg, *bb;
  unsigned short* yr;
  if (row < BB * LQ) {
    xr = xq + (size_t)row * DD; gg = gq; bb = bq; yr = yq + (size_t)row * DD;
  } else {
    int r = row - BB * LQ;
    xr = xkv + (size_t)r * DD; gg = gkv; bb = bkv; yr = ykv + (size_t)r * DD;
  }
  float v0 = xr[t], v1 = xr[t + 256], v2 = xr[t + 512];
  __shared__ float red[4];
  float s = v0 + v1 + v2;
  #pragma unroll
  for (int o = 32; o > 0; o >>= 1) s += __shfl_xor(s, o);
  if ((t & 63) == 0) red[t >> 6] = s;
  __syncthreads();
  float m = (red[0] + red[1] + red[2] + red[3]) * (1.0f / 768.0f);
  float e0 = v0 - m, e1 = v1 - m, e2 = v2 - m;
  float s2v = e0 * e0 + e1 * e1 + e2 * e2;
  #pragma unroll
  for (int o = 32; o > 0; o >>= 1) s2v += __shfl_xor(s2v, o);
  __syncthreads();
  if ((t & 63) == 0) red[t >> 6] = s2v;
  __syncthreads();
  float var = (red[0] + red[1] + red[2] + red[3]) * (1.0f / 768.0f);
  float rs = rsqrtf(var + 1e-5f);
  yr[t]       = f2bf(e0 * rs * gg[t]       + bb[t]);
  yr[t + 256] = f2bf(e1 * rs * gg[t + 256] + bb[t + 256]);
  yr[t + 512] = f2bf(e2 * rs * gg[t + 512] + bb[t + 512]);
}

// ===== common GEMM machinery (counted-vmcnt 2-phase, T4; asm ds_read) =====

#define COMMON_PREAMBLE()                                                      \
  const int tid = threadIdx.x;                                                 \
  const int w = tid >> 6, l = tid & 63;                                        \
  const int lq = l & 15, g = l >> 4;                                           \
  const int srow = l >> 3;                                                     \
  const int scol = ((l & 7) * 16) ^ ((srow & 7) << 4);

// 8 VMEM per wave per stage (4 A + 4 B); 128x128 tile, BK=64
#define STAGE2(BUFI, T)                                                        \
  {                                                                            \
    int k0s = (T) * 64;                                                        \
    _Pragma("unroll")                                                          \
    for (int it = 0; it < 4; ++it) {                                           \
      int rbase = it * 32 + w * 8;                                             \
      gload_lds16(Asrc + (size_t)rbase * DD + k0s, &As[BUFI][rbase * 64]);     \
      gload_lds16(Bsrc + (size_t)rbase * DD + k0s, &Bs[BUFI][rbase * 64]);     \
    }                                                                          \
  }

#define COMPUTE2(BUFI)                                                         \
  {                                                                            \
    bf16x8 a[4][2], b[4][2];                                                   \
    _Pragma("unroll")                                                          \
    for (int mi = 0; mi < 4; ++mi)                                             \
      _Pragma("unroll")                                                        \
      for (int ks = 0; ks < 2; ++ks) {                                         \
        a[mi][ks] = lds_read16(&As[BUFI][aoff[mi][ks]]);                       \
        b[mi][ks] = lds_read16(&Bs[BUFI][boff[mi][ks]]);                       \
      }                                                                        \
    asm volatile("s_waitcnt lgkmcnt(0)" ::: "memory");                         \
    __builtin_amdgcn_sched_barrier(0);                                         \
    _Pragma("unroll")                                                          \
    for (int ks = 0; ks < 2; ++ks)                                             \
      _Pragma("unroll")                                                        \
      for (int mi = 0; mi < 4; ++mi)                                           \
        _Pragma("unroll")                                                      \
        for (int ni = 0; ni < 4; ++ni)                                         \
          acc[mi][ni] = __builtin_amdgcn_mfma_f32_16x16x32_bf16(               \
              a[mi][ks], b[ni][ks], acc[mi][ni], 0, 0, 0);                     \
  }

#define GEMM_MAIN()                                                            \
  int aoff[4][2], boff[4][2];                                                  \
  _Pragma("unroll")                                                            \
  for (int mi = 0; mi < 4; ++mi) {                                             \
    int rowa = wr * 64 + mi * 16 + lq;                                         \
    int rowb = wc * 64 + mi * 16 + lq;                                         \
    _Pragma("unroll")                                                          \
    for (int ks = 0; ks < 2; ++ks) {                                           \
      aoff[mi][ks] = rowa * 64 + (((ks * 64 + g * 16) ^ ((rowa & 7) << 4)) >> 1); \
      boff[mi][ks] = rowb * 64 + (((ks * 64 + g * 16) ^ ((rowb & 7) << 4)) >> 1); \
    }                                                                          \
  }                                                                            \
  STAGE2(0, 0);                                                                \
  STAGE2(1, 1);                                                                \
  _Pragma("unroll")                                                            \
  for (int t = 0; t < 12; ++t) {                                               \
    if (t < 11) asm volatile("s_waitcnt vmcnt(8)" ::: "memory");               \
    else        asm volatile("s_waitcnt vmcnt(0)" ::: "memory");               \
    __builtin_amdgcn_sched_barrier(0);                                         \
    __builtin_amdgcn_s_barrier();                                              \
    if ((t & 1) == 0) { COMPUTE2(0); } else { COMPUTE2(1); }                   \
    __builtin_amdgcn_s_barrier();                                              \
    __builtin_amdgcn_sched_barrier(0);                                         \
    if (t + 2 < 12) {                                                          \
      if ((t & 1) == 0) { STAGE2(0, t + 2); } else { STAGE2(1, t + 2); }       \
    }                                                                          \
  }

// ---------------- gate-score GEMM: GS[8192,16] = xkv_n * U^T ----------------
__global__ __launch_bounds__(256) void gs_gemm(const unsigned short* __restrict__ xkvb,
                                               const unsigned short* __restrict__ UB,
                                               float* __restrict__ GS) {
  __shared__ __align__(16) unsigned short Xs[2][64 * 64];
  __shared__ __align__(16) unsigned short Us[2][16 * 64];
  COMMON_PREAMBLE();
  const int bm = blockIdx.x * 64;
  const unsigned short* Asrc = xkvb + (size_t)(bm + srow) * DD + (scol >> 1);
  const unsigned short* Us0 = UB + (size_t)srow * DD + (scol >> 1);
  const unsigned short* Us1 = UB + (size_t)(8 + srow) * DD + (scol >> 1);

#define GS_STAGE(BUFI, T)                                                      \
  {                                                                            \
    int k0s = (T) * 64;                                                        \
    _Pragma("unroll")                                                          \
    for (int it = 0; it < 2; ++it) {                                           \
      int rbase = it * 32 + w * 8;                                             \
      gload_lds16(Asrc + (size_t)rbase * DD + k0s, &Xs[BUFI][rbase * 64]);     \
    }                                                                          \
    gload_lds16(Us0 + k0s, &Us[BUFI][0]);                                      \
    gload_lds16(Us1 + k0s, &Us[BUFI][8 * 64]);                                 \
  }

  f32x4 acc = {};

#define GS_COMPUTE(BUFI)                                                       \
  {                                                                            \
    bf16x8 a[2], b[2];                                                         \
    _Pragma("unroll")                                                          \
    for (int ks = 0; ks < 2; ++ks) {                                           \
      int arow = w * 16 + lq;                                                  \
      int acb = (ks * 64 + g * 16) ^ ((arow & 7) << 4);                        \
      a[ks] = lds_read16(&Xs[BUFI][arow * 64 + (acb >> 1)]);                   \
      int brow = lq;                                                           \
      int bcb = (ks * 64 + g * 16) ^ ((brow & 7) << 4);                        \
      b[ks] = lds_read16(&Us[BUFI][brow * 64 + (bcb >> 1)]);                   \
    }                                                                          \
    asm volatile("s_waitcnt lgkmcnt(0)" ::: "memory");                         \
    __builtin_amdgcn_sched_barrier(0);                                         \
    _Pragma("unroll")                                                          \
    for (int ks = 0; ks < 2; ++ks)                                             \
      acc = __builtin_amdgcn_mfma_f32_16x16x32_bf16(a[ks], b[ks], acc, 0, 0, 0); \
  }

  GS_STAGE(0, 0);
  GS_STAGE(1, 1);
  #pragma unroll
  for (int t = 0; t < 12; ++t) {
    if (t < 11) asm volatile("s_waitcnt vmcnt(4)" ::: "memory");
    else        asm volatile("s_waitcnt vmcnt(0)" ::: "memory");
    __builtin_amdgcn_sched_barrier(0);
    __builtin_amdgcn_s_barrier();
    if ((t & 1) == 0) { GS_COMPUTE(0); } else { GS_COMPUTE(1); }
    __builtin_amdgcn_s_barrier();
    __builtin_amdgcn_sched_barrier(0);
    if (t + 2 < 12) {
      if ((t & 1) == 0) { GS_STAGE(0, t + 2); } else { GS_STAGE(1, t + 2); }
    }
  }
  #pragma unroll
  for (int r = 0; r < 4; ++r)
    GS[(size_t)(bm + w * 16 + g * 4 + r) * 16 + lq] = acc[r];
}

// ---------------- Gate + top-k (scores precomputed; g = sum p*s) ----------------
__global__ __launch_bounds__(512) void gate_topk(const float* __restrict__ GS,
                                                 const int* __restrict__ mask,
                                                 int* __restrict__ idxo,
                                                 float* __restrict__ vbias,
                                                 float* __restrict__ ndv,
                                                 float* __restrict__ g_h) {
  int bh = blockIdx.x, b = bh / HH, h = bh % HH;
  int l = threadIdx.x;
  __shared__ __align__(16) float s_sc[512];
  __shared__ float red[8];
  __shared__ int wred[8];
  float sc = GS[(size_t)(b * LT + l) * 16 + h];
  bool maskv = (mask[b * LT + l] != 0);
  if (!maskv) sc = -INFINITY;
  s_sc[l] = sc;
  float m0 = sc;
  #pragma unroll
  for (int o = 32; o > 0; o >>= 1) m0 = fmaxf(m0, __shfl_xor(m0, o));
  if ((l & 63) == 0) red[l >> 6] = m0;
  __syncthreads();
  float m = red[0];
  #pragma unroll
  for (int w = 1; w < 8; w++) m = fmaxf(m, red[w]);
  float p = __expf(sc - m);
  float s1 = p;
  #pragma unroll
  for (int o = 32; o > 0; o >>= 1) s1 += __shfl_xor(s1, o);
  __syncthreads();
  if ((l & 63) == 0) red[l >> 6] = s1;
  __syncthreads();
  float Z = 0.0f;
  #pragma unroll
  for (int w = 0; w < 8; w++) Z += red[w];
  p /= Z;
  float gc = maskv ? p * sc : 0.0f;
  #pragma unroll
  for (int o = 32; o > 0; o >>= 1) gc += __shfl_xor(gc, o);
  __syncthreads();
  if ((l & 63) == 0) red[l >> 6] = gc;
  __syncthreads();
  if (l == 0) {
    float G = 0.0f;
    #pragma unroll
    for (int w = 0; w < 8; w++) G += red[w];
    g_h[bh] = 1.0f / (1.0f + __expf(-G));
  }
  // stable rank (matches jax.lax.top_k tie-breaking), float4-vectorized LDS reads
  float my = s_sc[l];
  int cnt = 0;
  for (int j4 = 0; j4 < LT; j4 += 4) {
    float4 s4 = *reinterpret_cast<const float4*>(&s_sc[j4]);
    cnt += (s4.x > my || (s4.x == my && (j4 + 0) < l)) ? 1 : 0;
    cnt += (s4.y > my || (s4.y == my && (j4 + 1) < l)) ? 1 : 0;
    cnt += (s4.z > my || (s4.z == my && (j4 + 2) < l)) ? 1 : 0;
    cnt += (s4.w > my || (s4.w == my && (j4 + 3) < l)) ? 1 : 0;
  }
  if (cnt < TOPK) {
    idxo[bh * TOPK + cnt] = l;
    vbias[bh * TOPK + cnt] = maskv ? 0.0f : -INFINITY;
  }
  int dv = (maskv && cnt >= TOPK) ? 1 : 0;
  unsigned long long bal = __ballot(dv);
  if ((l & 63) == 0) wred[l >> 6] = __popcll(bal);
  __syncthreads();
  if (l == 0) {
    int nd = 0;
    #pragma unroll
    for (int w = 0; w < 8; w++) nd += wred[w];
    ndv[bh] = (float)nd;
  }
}

// ---------------- fused: Q projection (432 blocks) + compact K&V gather-GEMM (192 blocks) ----------------
__global__ __launch_bounds__(256, 2) void proj2(const unsigned short* __restrict__ xqb,
                                                const unsigned short* __restrict__ wqb,
                                                const unsigned short* __restrict__ xkvb,
                                                const unsigned short* __restrict__ wkb,
                                                const unsigned short* __restrict__ wvb,
                                                const int* __restrict__ idxo,
                                                unsigned short* __restrict__ QBF,
                                                unsigned short* __restrict__ KC,
                                                unsigned short* __restrict__ VCT) {
  __shared__ __align__(16) unsigned short As[2][128 * 64];
  __shared__ __align__(16) unsigned short Bs[2][128 * 64];
  __shared__ int sidx[64];
  COMMON_PREAMBLE();
  int p = blockIdx.x;                       // 624 = 8 * 78
  int bid = (p & 7) * 78 + (p >> 3);

  if (bid < 432) {
    // ---- Q projection, 128x128 tile ----
    const int wr = w >> 1, wc = w & 1;
    const int mtile = bid / 6, nt = bid % 6;
    const int bm = mtile * 128, bn = nt * 128;
    const unsigned short* Asrc = xqb + (size_t)(bm + srow) * DD + (scol >> 1);
    const unsigned short* Bsrc = wqb + (size_t)(bn + srow) * DD + (scol >> 1);
    f32x4 acc[4][4] = {};
    GEMM_MAIN();
    const int m_base = bm + wr * 64, n_base = bn + wc * 64;
    #pragma unroll
    for (int mi = 0; mi < 4; ++mi)
      #pragma unroll
      for (int r = 0; r < 4; ++r) {
        int m = m_base + mi * 16 + g * 4 + r;
        #pragma unroll
        for (int ni = 0; ni < 4; ++ni) {
          int n = n_base + ni * 16 + lq;
          QBF[(size_t)m * DD + n] = f2bf(acc[mi][ni][r] * 0.125f);
        }
      }
  } else {
    // ---- compact K & V: per (b,h), Kc[j,d] / Vct[d,j], 64x64x768 gather-GEMM ----
    const int bh = bid - 432, b = bh / HH, h = bh % HH;
    if (tid < 64) sidx[tid] = idxo[bh * TOPK + tid];
    __syncthreads();
    unsigned short* Xs0 = &As[0][0]; unsigned short* Xs1 = &As[0][4096];
    unsigned short* Kp0 = &As[1][0]; unsigned short* Kp1 = &As[1][4096];
    unsigned short* Vp0 = &Bs[0][0]; unsigned short* Vp1 = &Bs[0][4096];
    const int j0 = w * 16 + srow, j1 = w * 16 + 8 + srow;
    const unsigned short* xs0 = xkvb + (size_t)(b * LT + sidx[j0]) * DD + (scol >> 1);
    const unsigned short* xs1 = xkvb + (size_t)(b * LT + sidx[j1]) * DD + (scol >> 1);
    const unsigned short* wk0 = wkb + (size_t)(h * DH + j0) * DD + (scol >> 1);
    const unsigned short* wk1 = wkb + (size_t)(h * DH + j1) * DD + (scol >> 1);
    const unsigned short* wv0 = wvb + (size_t)(h * DH + j0) * DD + (scol >> 1);
    const unsigned short* wv1 = wvb + (size_t)(h * DH + j1) * DD + (scol >> 1);

#define KV_STAGE(Xd, Kd, Vd, T)                                                \
    {                                                                          \
      int k0s = (T) * 64;                                                      \
      gload_lds16(xs0 + k0s, Xd + (w * 16) * 64);                              \
      gload_lds16(xs1 + k0s, Xd + (w * 16 + 8) * 64);                          \
      gload_lds16(wk0 + k0s, Kd + (w * 16) * 64);                              \
      gload_lds16(wk1 + k0s, Kd + (w * 16 + 8) * 64);                          \
      gload_lds16(wv0 + k0s, Vd + (w * 16) * 64);                              \
      gload_lds16(wv1 + k0s, Vd + (w * 16 + 8) * 64);                          \
    }

    f32x4 accK[4] = {}, accV[4] = {};

#define KV_COMPUTE(Xd, Kd, Vd)                                                 \
    {                                                                          \
      bf16x8 ax[2], av[2], bk[4][2], bx[4][2];                                 \
      _Pragma("unroll")                                                        \
      for (int ks = 0; ks < 2; ++ks) {                                         \
        int arow = w * 16 + lq;                                                \
        int acb = (ks * 64 + g * 16) ^ ((arow & 7) << 4);                      \
        ax[ks] = lds_read16(Xd + arow * 64 + (acb >> 1));                      \
        av[ks] = lds_read16(Vd + arow * 64 + (acb >> 1));                      \
        _Pragma("unroll")                                                      \
        for (int ni = 0; ni < 4; ++ni) {                                       \
          int brow = ni * 16 + lq;                                             \
          int bcb = (ks * 64 + g * 16) ^ ((brow & 7) << 4);                    \
          bk[ni][ks] = lds_read16(Kd + brow * 64 + (bcb >> 1));                \
          bx[ni][ks] = lds_read16(Xd + brow * 64 + (bcb >> 1));                \
        }                                                                      \
      }                                                                        \
      asm volatile("s_waitcnt lgkmcnt(0)" ::: "memory");                       \
      __builtin_amdgcn_sched_barrier(0);                                       \
      _Pragma("unroll")                                                        \
      for (int ks = 0; ks < 2; ++ks)                                           \
        _Pragma("unroll")                                                      \
        for (int ni = 0; ni < 4; ++ni) {                                       \
          accK[ni] = __builtin_amdgcn_mfma_f32_16x16x32_bf16(ax[ks], bk[ni][ks], accK[ni], 0, 0, 0); \
          accV[ni] = __builtin_amdgcn_mfma_f32_16x16x32_bf16(av[ks], bx[ni][ks], accV[ni], 0, 0, 0); \
        }                                                                      \
    }

    KV_STAGE(Xs0, Kp0, Vp0, 0);
    KV_STAGE(Xs1, Kp1, Vp1, 1);
    #pragma unroll
    for (int t = 0; t < 12; ++t) {
      if (t < 11) asm volatile("s_waitcnt vmcnt(6)" ::: "memory");
      else        asm volatile("s_waitcnt vmcnt(0)" ::: "memory");
      __builtin_amdgcn_sched_barrier(0);
      __builtin_amdgcn_s_barrier();
      if ((t & 1) == 0) { KV_COMPUTE(Xs0, Kp0, Vp0); } else { KV_COMPUTE(Xs1, Kp1, Vp1); }
      __builtin_amdgcn_s_barrier();
      __builtin_amdgcn_sched_barrier(0);
      if (t + 2 < 12) {
        if ((t & 1) == 0) { KV_STAGE(Xs0, Kp0, Vp0, t + 2); } else { KV_STAGE(Xs1, Kp1, Vp1, t + 2); }
      }
    }
    #pragma unroll
    for (int ni = 0; ni < 4; ++ni)
      #pragma unroll
      for (int r = 0; r < 4; ++r) {
        int mrow = w * 16 + g * 4 + r;
        KC [(size_t)bh * 4096 + mrow * 64 + ni * 16 + lq] = f2bf(accK[ni][r]);
        VCT[(size_t)bh * 4096 + mrow * 64 + ni * 16 + lq] = f2bf(accV[ni][r]);
      }
  }
}

// ---------------- output projection GEMM + residual epilogue ----------------
__global__ __launch_bounds__(256, 2) void o_gemm(const unsigned short* __restrict__ ABF,
                                                 const unsigned short* __restrict__ wob,
                                                 float* __restrict__ out,
                                                 const float* __restrict__ resid,
                                                 const float* __restrict__ gl) {
  __shared__ __align__(16) unsigned short As[2][128 * 64];
  __shared__ __align__(16) unsigned short Bs[2][128 * 64];
  COMMON_PREAMBLE();
  const int wr = w >> 1, wc = w & 1;
  int p = blockIdx.x;                     // 432 = 8 * 54
  int bid = (p & 7) * 54 + (p >> 3);
  const int mtile = bid / 6, nt = bid % 6;
  const int bm = mtile * 128, bn = nt * 128;
  const unsigned short* Asrc = ABF + (size_t)(bm + srow) * DD + (scol >> 1);
  const unsigned short* Bsrc = wob + (size_t)(bn + srow) * DD + (scol >> 1);

  f32x4 acc[4][4] = {};
  GEMM_MAIN();

  float alpha = 1.0f / (1.0f + __expf(-gl[0]));
  const int m_base = bm + wr * 64, n_base = bn + wc * 64;
  #pragma unroll
  for (int mi = 0; mi < 4; ++mi)
    #pragma unroll
    for (int r = 0; r < 4; ++r) {
      int m = m_base + mi * 16 + g * 4 + r;
      #pragma unroll
      for (int ni = 0; ni < 4; ++ni) {
        int n = n_base + ni * 16 + lq;
        out[(size_t)m * DD + n] = resid[(size_t)m * DD + n] + alpha * acc[mi][ni][r];
      }
    }
}

// ---------------- Top-k attention: single 64-key tile, closed-form dropped-mass correction ----------------
__global__ __launch_bounds__(256) void attn_topk(const unsigned short* __restrict__ Qb,
                                                 const unsigned short* __restrict__ KC,
                                                 const unsigned short* __restrict__ VCT,
                                                 const float* __restrict__ vbias,
                                                 const float* __restrict__ ndv,
                                                 const float* __restrict__ g_h,
                                                 unsigned short* __restrict__ att) {
  const int bh = blockIdx.y, b = bh / HH, h = bh % HH;
  const int q0 = blockIdx.x * 64;
  const int tid = threadIdx.x;
  const int w = tid >> 6, l = tid & 63;
  const int lq = l & 15, g = l >> 4;

  __shared__ __align__(16) unsigned short Klds[64 * 64];
  __shared__ __align__(16) unsigned short Vlds[64 * 64];
  __shared__ float svb[64];

  const int srow = l >> 3;
  const int scol = ((l & 7) * 16) ^ ((srow & 7) << 4);
  #pragma unroll
  for (int it = 0; it < 2; ++it) {
    int rbase = w * 16 + it * 8;
    gload_lds16(KC  + (size_t)bh * 4096 + (rbase + srow) * 64 + (scol >> 1), &Klds[rbase * 64]);
    gload_lds16(VCT + (size_t)bh * 4096 + (rbase + srow) * 64 + (scol >> 1), &Vlds[rbase * 64]);
  }
  if (tid < 64) svb[tid] = vbias[bh * TOPK + tid];

  bf16x8 qf0, qf1;
  {
    const unsigned short* qrow =
        Qb + ((size_t)(b * LQ + q0 + w * 16 + lq)) * DD + h * DH + g * 8;
    qf0 = *reinterpret_cast<const bf16x8*>(qrow);
    qf1 = *reinterpret_cast<const bf16x8*>(qrow + 32);
  }
  __syncthreads();

  f32x4 S[4];
  #pragma unroll
  for (int kt = 0; kt < 4; ++kt) {
    f32x4 acc = {};
    int row = kt * 16 + lq;
    int c0 = (g * 16) ^ ((row & 7) << 4);
    int c1 = (64 + g * 16) ^ ((row & 7) << 4);
    bf16x8 a0 = *reinterpret_cast<const bf16x8*>(&Klds[row * 64 + (c0 >> 1)]);
    bf16x8 a1 = *reinterpret_cast<const bf16x8*>(&Klds[row * 64 + (c1 >> 1)]);
    acc = __builtin_amdgcn_mfma_f32_16x16x32_bf16(a0, qf0, acc, 0, 0, 0);
    acc = __builtin_amdgcn_mfma_f32_16x16x32_bf16(a1, qf1, acc, 0, 0, 0);
    S[kt] = acc;
  }

  float s_v[16];
  float mx = -INFINITY;
  #pragma unroll
  for (int kt = 0; kt < 4; ++kt)
    #pragma unroll
    for (int r = 0; r < 4; ++r) {
      float s = S[kt][r] + svb[kt * 16 + g * 4 + r];
      s_v[kt * 4 + r] = s;
      mx = fmaxf(mx, s);
    }
  mx = fmaxf(mx, __shfl_xor(mx, 16));
  mx = fmaxf(mx, __shfl_xor(mx, 32));
  float nd = ndv[bh];
  float m2 = (nd > 0.0f) ? fmaxf(mx, 0.0f) : mx;

  float psum = 0.0f;
  unsigned short pb[16];
  #pragma unroll
  for (int i = 0; i < 16; ++i) {
    float p = __expf(s_v[i] - m2);
    psum += p;
    pb[i] = f2bf(p);
  }
  psum += __shfl_xor(psum, 16);
  psum += __shfl_xor(psum, 32);
  float Z = psum + nd * __expf(-m2);
  float inv = 1.0f / Z;

  bf16x8 pa0, pa1;
  #pragma unroll
  for (int j = 0; j < 8; ++j) { pa0[j] = (short)pb[j]; pa1[j] = (short)pb[8 + j]; }

  f32x4 O[4] = {};
  #pragma unroll
  for (int dt = 0; dt < 4; ++dt) {
    int r = dt * 16 + lq;
    int swz = (r & 7) << 4;
    #pragma unroll
    for (int ks = 0; ks < 2; ++ks) {
      int cl = (64 * ks + g * 8) ^ swz;
      int ch = (64 * ks + 32 + g * 8) ^ swz;
      u16x4 lo = *reinterpret_cast<const u16x4*>(&Vlds[r * 64 + (cl >> 1)]);
      u16x4 hi = *reinterpret_cast<const u16x4*>(&Vlds[r * 64 + (ch >> 1)]);
      bf16x8 vb = { (short)lo[0], (short)lo[1], (short)lo[2], (short)lo[3],
                    (short)hi[0], (short)hi[1], (short)hi[2], (short)hi[3] };
      O[dt] = __builtin_amdgcn_mfma_f32_16x16x32_bf16(ks == 0 ? pa0 : pa1, vb, O[dt], 0, 0, 0);
    }
  }

  float invl[4];
  #pragma unroll
  for (int r = 0; r < 4; ++r) invl[r] = __shfl(inv, g * 4 + r);
  float gh = g_h[bh];
  #pragma unroll
  for (int dt = 0; dt < 4; ++dt)
    #pragma unroll
    for (int r = 0; r < 4; ++r) {
      int q = q0 + w * 16 + g * 4 + r;
      att[((size_t)(b * LQ + q)) * DD + h * DH + dt * 16 + lq] =
          f2bf(O[dt][r] * invl[r] * gh);
    }
}

extern "C" void kernel_launch(void* const* d_in, const int* in_sizes, int n_in,
                              void* d_out, int out_size, void* d_ws, size_t ws_size,
                              hipStream_t stream) {
  const float* x_q      = (const float*)d_in[0];
  const float* x_kv     = (const float*)d_in[1];
  const int*   mask     = (const int*)d_in[2];
  const float* wq       = (const float*)d_in[3];
  const float* wk       = (const float*)d_in[4];
  const float* wv       = (const float*)d_in[5];
  const float* wo       = (const float*)d_in[6];
  const float* ln_q_g   = (const float*)d_in[7];
  const float* ln_q_b   = (const float*)d_in[8];
  const float* ln_kv_g  = (const float*)d_in[9];
  const float* ln_kv_b  = (const float*)d_in[10];
  const float* hq       = (const float*)d_in[11];
  const float* resid_l  = (const float*)d_in[12];
  float* out = (float*)d_out;
  float* ws  = (float*)d_ws;

  unsigned short* xqb  = (unsigned short*)(ws + XQBF);
  unsigned short* xkvb = (unsigned short*)(ws + XKVBF);
  unsigned short* wqb  = (unsigned short*)(ws + WQB);
  unsigned short* wkb  = (unsigned short*)(ws + WKB);
  unsigned short* wvb  = (unsigned short*)(ws + WVB);
  unsigned short* wob  = (unsigned short*)(ws + WOB);
  unsigned short* QBF  = (unsigned short*)(ws + QBFo);
  unsigned short* UB   = (unsigned short*)(ws + UBo);
  float*          GS   = (float*)(ws + GSo);
  int*            IDX  = (int*)(ws + IDXo);
  unsigned short* KC   = (unsigned short*)(ws + KCo);
  unsigned short* VCT  = (unsigned short*)(ws + VCTo);
  unsigned short* ABF  = xqb;   // reuse xq_n slot after Q-GEMM

  // fused LN + weight-convert + u-precompute (independent block ranges)
  ln_conv<<<dim3(BB * LQ + BB * LT + 2880), dim3(256), 0, stream>>>(
      x_q, x_kv, ln_q_g, ln_q_b, ln_kv_g, ln_kv_b, xqb, xkvb,
      wq, wk, wv, wo, wqb, wkb, wvb, wob, hq, UB);

  gs_gemm<<<dim3(128), dim3(256), 0, stream>>>(xkvb, UB, GS);

  gate_topk<<<dim3(BB * HH), dim3(512), 0, stream>>>(GS, mask, IDX,
                                                     ws + VBIA, ws + NDVo, ws + GHo);

  proj2<<<dim3(624), dim3(256), 0, stream>>>(xqb, wqb, xkvb, wkb, wvb, IDX, QBF, KC, VCT);

  attn_topk<<<dim3(LQ / 64, BB * HH), dim3(256), 0, stream>>>(QBF, KC, VCT,
                                                              ws + VBIA, ws + NDVo, ws + GHo, ABF);

  o_gemm<<<dim3(432), dim3(256), 0, stream>>>(ABF, wob, out, x_q, resid_l);
}